// Round 1
// baseline (1603.950 us; speedup 1.0000x reference)
//
#include <hip/hip_runtime.h>
#include <math.h>

#define GHEADS 4

__device__ __forceinline__ unsigned fenc(float f) {
    unsigned u = __float_as_uint(f);
    return (u & 0x80000000u) ? ~u : (u | 0x80000000u);
}
__device__ __forceinline__ float fdec(unsigned u) {
    return (u & 0x80000000u) ? __uint_as_float(u & 0x7fffffffu) : __uint_as_float(~u);
}

// ---------------- GEMM: H[n, OUT] = X[n, K] @ W[K, OUT] ----------------
// One block computes 8 rows; OUT threads, thread t owns column t for all 8 rows.
template<int OUT, int K>
__global__ void __launch_bounds__(OUT) gemm_kernel(const float* __restrict__ X,
                                                   const float* __restrict__ W,
                                                   float* __restrict__ H, int n) {
    __shared__ float xs[8][K];
    const int row0 = blockIdx.x * 8;
    const int tid = threadIdx.x;
    const int rows = (n - row0 < 8) ? (n - row0) : 8;
    for (int i = tid; i < rows * K; i += OUT) {
        int r = i / K, k = i % K;
        xs[r][k] = X[(size_t)(row0 + r) * K + k];
    }
    __syncthreads();
    float acc[8] = {0.f,0.f,0.f,0.f,0.f,0.f,0.f,0.f};
    for (int k = 0; k < K; ++k) {
        float w = W[k * OUT + tid];
#pragma unroll
        for (int r = 0; r < 8; ++r) acc[r] += xs[r][k] * w;
    }
    for (int r = 0; r < rows; ++r) H[(size_t)(row0 + r) * OUT + tid] = acc[r];
}

// ---------------- per-(node,head) attention dots ----------------
template<int C>
__global__ void attdot_kernel(const float* __restrict__ H,
                              const float* __restrict__ as_, const float* __restrict__ ad_,
                              float* __restrict__ asrc, float* __restrict__ adst, int n) {
    int i = blockIdx.x * blockDim.x + threadIdx.x;
    if (i >= n * GHEADS) return;
    int node = i >> 2, h = i & 3;
    const float* hp = H + (size_t)node * (GHEADS * C) + h * C;
    float s1 = 0.f, s2 = 0.f;
#pragma unroll 8
    for (int c = 0; c < C; ++c) {
        float v = hp[c];
        s1 += v * as_[h * C + c];
        s2 += v * ad_[h * C + c];
    }
    asrc[i] = s1;
    adst[i] = s2;
}

// ---------------- edge pass 1: segment max ----------------
__global__ void edge_max_kernel(const int* __restrict__ src, const int* __restrict__ dst,
                                int E, int n,
                                const float* __restrict__ asrc, const float* __restrict__ adst,
                                unsigned* __restrict__ amax) {
    int i = blockIdx.x * blockDim.x + threadIdx.x;
    int total = (E + n) * GHEADS;
    if (i >= total) return;
    int e = i >> 2, h = i & 3;
    int s = (e < E) ? src[e] : (e - E);
    int d = (e < E) ? dst[e] : (e - E);
    float a = asrc[s * GHEADS + h] + adst[d * GHEADS + h];
    a = (a > 0.f) ? a : 0.2f * a;   // leaky relu
    atomicMax(amax + d * GHEADS + h, fenc(a));
}

// ---------------- edge pass 2: exp + segment sum ----------------
__global__ void edge_exp_kernel(const int* __restrict__ src, const int* __restrict__ dst,
                                int E, int n,
                                const float* __restrict__ asrc, const float* __restrict__ adst,
                                const unsigned* __restrict__ amax,
                                float* __restrict__ eexp, float* __restrict__ denom) {
    int i = blockIdx.x * blockDim.x + threadIdx.x;
    int total = (E + n) * GHEADS;
    if (i >= total) return;
    int e = i >> 2, h = i & 3;
    int s = (e < E) ? src[e] : (e - E);
    int d = (e < E) ? dst[e] : (e - E);
    float a = asrc[s * GHEADS + h] + adst[d * GHEADS + h];
    a = (a > 0.f) ? a : 0.2f * a;
    float ev = expf(a - fdec(amax[d * GHEADS + h]));
    eexp[i] = ev;
    atomicAdd(denom + d * GHEADS + h, ev);
}

// ---------------- edge pass 3: scatter-aggregate ----------------
// one wavefront (64 lanes) per edge; OUT elements per edge.
template<int OUT>
__global__ void scatter_kernel(const int* __restrict__ src, const int* __restrict__ dst,
                               int E, int n,
                               const float* __restrict__ eexp, const float* __restrict__ denom,
                               const float* __restrict__ H, float* __restrict__ Out) {
    const int C = OUT / GHEADS;
    int wave = (blockIdx.x * blockDim.x + threadIdx.x) >> 6;
    int lane = threadIdx.x & 63;
    if (wave >= E + n) return;
    int e = wave;
    int s = (e < E) ? src[e] : (e - E);
    int d = (e < E) ? dst[e] : (e - E);
    for (int j = lane; j < OUT; j += 64) {
        int h = j / C;
        float coef = eexp[e * GHEADS + h] / denom[d * GHEADS + h];
        atomicAdd(Out + (size_t)d * OUT + j, H[(size_t)s * OUT + j] * coef);
    }
}

// ---------------- bias + relu (+ optional embedding copy) ----------------
__global__ void bias_relu_kernel(float* __restrict__ B, const float* __restrict__ bias,
                                 int n, int OUT, float* __restrict__ emb_out) {
    int i = blockIdx.x * blockDim.x + threadIdx.x;
    if (i >= n * OUT) return;
    float v = B[i] + bias[i % OUT];
    v = fmaxf(v, 0.f);
    B[i] = v;
    if (emb_out) emb_out[i] = v;
}

// ---------------- layer-3 epilogue: head-mean + bias + log_softmax ----------------
__global__ void final_kernel(const float* __restrict__ B, const float* __restrict__ b3,
                             float* __restrict__ out, int n) {
    int node = blockIdx.x * blockDim.x + threadIdx.x;
    if (node >= n) return;
    float v[40];
    float mx = -1e30f;
#pragma unroll
    for (int c = 0; c < 40; ++c) {
        float s = 0.f;
        for (int h = 0; h < 4; ++h) s += B[(size_t)node * 160 + h * 40 + c];
        s = 0.25f * s + b3[c];
        v[c] = s;
        mx = fmaxf(mx, s);
    }
    float sum = 0.f;
#pragma unroll
    for (int c = 0; c < 40; ++c) sum += expf(v[c] - mx);
    float lg = mx + logf(sum);
#pragma unroll
    for (int c = 0; c < 40; ++c) out[(size_t)node * 40 + c] = v[c] - lg;
}

extern "C" void kernel_launch(void* const* d_in, const int* in_sizes, int n_in,
                              void* d_out, int out_size, void* d_ws, size_t ws_size,
                              hipStream_t stream) {
    const float* x   = (const float*)d_in[0];
    const int*   ei  = (const int*)d_in[1];
    const float* W1  = (const float*)d_in[2];
    const float* as1 = (const float*)d_in[3];
    const float* ad1 = (const float*)d_in[4];
    const float* b1  = (const float*)d_in[5];
    const float* W2  = (const float*)d_in[6];
    const float* as2 = (const float*)d_in[7];
    const float* ad2 = (const float*)d_in[8];
    const float* b2  = (const float*)d_in[9];
    const float* W3  = (const float*)d_in[10];
    const float* as3 = (const float*)d_in[11];
    const float* ad3 = (const float*)d_in[12];
    const float* b3  = (const float*)d_in[13];

    const int n = in_sizes[0] / 128;      // 50000
    const int E = in_sizes[1] / 2;        // 800000
    const int ET = E + n;                 // with self loops
    const int* src = ei;
    const int* dst = ei + E;

    float* ws = (float*)d_ws;
    float*    A     = ws;                          // n*160 (GEMM output / h)
    float*    B     = A + (size_t)n * 160;         // n*160 (aggregation / layer io)
    float*    asrc  = B + (size_t)n * 160;         // n*4
    float*    adst  = asrc + (size_t)n * 4;        // n*4
    unsigned* amax  = (unsigned*)(adst + (size_t)n * 4);   // n*4
    float*    denom = (float*)amax + (size_t)n * 4;        // n*4
    float*    eexp  = denom + (size_t)n * 4;       // ET*4

    float* logits = (float*)d_out;                 // n*40
    float* emb    = logits + (size_t)n * 40;       // n*128

    const int BT = 256;
    const int nb_nh   = (n * GHEADS + BT - 1) / BT;
    const int nb_edge = (ET * GHEADS + BT - 1) / BT;
    const int nb_scat = (ET * 64 + BT - 1) / BT;   // one wave per edge
    const int nb_g8   = (n + 7) / 8;

    // ---------------- layer 1 ----------------
    gemm_kernel<128, 128><<<nb_g8, 128, 0, stream>>>(x, W1, A, n);
    attdot_kernel<32><<<nb_nh, BT, 0, stream>>>(A, as1, ad1, asrc, adst, n);
    hipMemsetAsync(amax, 0, (size_t)n * 4 * sizeof(unsigned), stream);
    hipMemsetAsync(denom, 0, (size_t)n * 4 * sizeof(float), stream);
    hipMemsetAsync(B, 0, (size_t)n * 128 * sizeof(float), stream);
    edge_max_kernel<<<nb_edge, BT, 0, stream>>>(src, dst, E, n, asrc, adst, amax);
    edge_exp_kernel<<<nb_edge, BT, 0, stream>>>(src, dst, E, n, asrc, adst, amax, eexp, denom);
    scatter_kernel<128><<<nb_scat, BT, 0, stream>>>(src, dst, E, n, eexp, denom, A, B);
    bias_relu_kernel<<<(n * 128 + BT - 1) / BT, BT, 0, stream>>>(B, b1, n, 128, nullptr);

    // ---------------- layer 2 ----------------
    gemm_kernel<128, 128><<<nb_g8, 128, 0, stream>>>(B, W2, A, n);
    attdot_kernel<32><<<nb_nh, BT, 0, stream>>>(A, as2, ad2, asrc, adst, n);
    hipMemsetAsync(amax, 0, (size_t)n * 4 * sizeof(unsigned), stream);
    hipMemsetAsync(denom, 0, (size_t)n * 4 * sizeof(float), stream);
    hipMemsetAsync(B, 0, (size_t)n * 128 * sizeof(float), stream);
    edge_max_kernel<<<nb_edge, BT, 0, stream>>>(src, dst, E, n, asrc, adst, amax);
    edge_exp_kernel<<<nb_edge, BT, 0, stream>>>(src, dst, E, n, asrc, adst, amax, eexp, denom);
    scatter_kernel<128><<<nb_scat, BT, 0, stream>>>(src, dst, E, n, eexp, denom, A, B);
    bias_relu_kernel<<<(n * 128 + BT - 1) / BT, BT, 0, stream>>>(B, b2, n, 128, emb);

    // ---------------- layer 3 ----------------
    gemm_kernel<160, 128><<<nb_g8, 160, 0, stream>>>(B, W3, A, n);
    attdot_kernel<40><<<nb_nh, BT, 0, stream>>>(A, as3, ad3, asrc, adst, n);
    hipMemsetAsync(amax, 0, (size_t)n * 4 * sizeof(unsigned), stream);
    hipMemsetAsync(denom, 0, (size_t)n * 4 * sizeof(float), stream);
    hipMemsetAsync(B, 0, (size_t)n * 160 * sizeof(float), stream);
    edge_max_kernel<<<nb_edge, BT, 0, stream>>>(src, dst, E, n, asrc, adst, amax);
    edge_exp_kernel<<<nb_edge, BT, 0, stream>>>(src, dst, E, n, asrc, adst, amax, eexp, denom);
    scatter_kernel<160><<<nb_scat, BT, 0, stream>>>(src, dst, E, n, eexp, denom, A, B);
    final_kernel<<<(n + 127) / 128, 128, 0, stream>>>(B, b3, logits, n);
}

// Round 2
// 729.148 us; speedup vs baseline: 2.1998x; 2.1998x over previous
//
#include <hip/hip_runtime.h>
#include <math.h>

#define GHEADS 4

// ---------------- GEMM: H[n, OUT] = X[n, K] @ W[K, OUT] ----------------
template<int OUT, int K>
__global__ void __launch_bounds__(OUT) gemm_kernel(const float* __restrict__ X,
                                                   const float* __restrict__ W,
                                                   float* __restrict__ H, int n) {
    __shared__ float xs[8][K];
    const int row0 = blockIdx.x * 8;
    const int tid = threadIdx.x;
    const int rows = (n - row0 < 8) ? (n - row0) : 8;
    for (int i = tid; i < rows * K; i += OUT) {
        int r = i / K, k = i % K;
        xs[r][k] = X[(size_t)(row0 + r) * K + k];
    }
    __syncthreads();
    float acc[8] = {0.f,0.f,0.f,0.f,0.f,0.f,0.f,0.f};
    for (int k = 0; k < K; ++k) {
        float w = W[k * OUT + tid];
#pragma unroll
        for (int r = 0; r < 8; ++r) acc[r] += xs[r][k] * w;
    }
    for (int r = 0; r < rows; ++r) H[(size_t)(row0 + r) * OUT + tid] = acc[r];
}

// ---------------- per-(node,head) attention dots ----------------
template<int C>
__global__ void attdot_kernel(const float* __restrict__ H,
                              const float* __restrict__ as_, const float* __restrict__ ad_,
                              float* __restrict__ asrc, float* __restrict__ adst, int n) {
    int i = blockIdx.x * blockDim.x + threadIdx.x;
    if (i >= n * GHEADS) return;
    int node = i >> 2, h = i & 3;
    const float* hp = H + (size_t)node * (GHEADS * C) + h * C;
    float s1 = 0.f, s2 = 0.f;
#pragma unroll 8
    for (int c = 0; c < C; ++c) {
        float v = hp[c];
        s1 += v * as_[h * C + c];
        s2 += v * ad_[h * C + c];
    }
    asrc[i] = s1;
    adst[i] = s2;
}

// ---------------- CSR build ----------------
__global__ void hist_kernel(const int* __restrict__ dst, int E, int* __restrict__ counts) {
    int i = blockIdx.x * blockDim.x + threadIdx.x;
    if (i < E) atomicAdd(&counts[dst[i]], 1);
}

// single block, 1024 threads: exclusive scan counts[n] -> rowptr[n+1]
__global__ void __launch_bounds__(1024) scan_kernel(const int* __restrict__ counts,
                                                    int* __restrict__ rowptr, int n) {
    __shared__ int ps[1024];
    const int tid = threadIdx.x;
    const int chunk = (n + 1023) >> 10;
    const int b = tid * chunk;
    const int e = (b + chunk < n) ? b + chunk : n;
    int s = 0;
    for (int i = b; i < e; ++i) s += counts[i];
    ps[tid] = s;
    __syncthreads();
    for (int off = 1; off < 1024; off <<= 1) {
        int v = (tid >= off) ? ps[tid - off] : 0;
        __syncthreads();
        ps[tid] += v;
        __syncthreads();
    }
    int run = (tid == 0) ? 0 : ps[tid - 1];
    for (int i = b; i < e; ++i) { rowptr[i] = run; run += counts[i]; }
    if (tid == 1023) rowptr[n] = ps[1023];
}

__global__ void place_kernel(const int* __restrict__ src, const int* __restrict__ dst,
                             int E, int* __restrict__ cursor, int* __restrict__ csrc) {
    int i = blockIdx.x * blockDim.x + threadIdx.x;
    if (i < E) {
        int p = atomicAdd(&cursor[dst[i]], 1);
        csrc[p] = src[i];
    }
}

// ---------------- fused softmax + gather-aggregate: one wave per dst node ----------------
template<int OUT, bool RELU>
__global__ void agg_kernel(const int* __restrict__ rowptr, const int* __restrict__ csrc,
                           const float* __restrict__ asrc, const float* __restrict__ adst,
                           const float* __restrict__ H, const float* __restrict__ bias,
                           float* __restrict__ Out, float* __restrict__ emb, int n) {
    const int C = OUT / GHEADS;
    const int CPL = (OUT + 63) / 64;   // channels per lane
    int wid = (blockIdx.x * blockDim.x + threadIdx.x) >> 6;
    int lane = threadIdx.x & 63;
    if (wid >= n) return;
    const int d = wid;
    const int h = lane & 3;
    const int rs = rowptr[d], re = rowptr[d + 1];

    const float adv = adst[d * 4 + h];
    float aself = asrc[d * 4 + h] + adv;
    aself = aself > 0.f ? aself : 0.2f * aself;

    // pass 1: per-head max (self-loop included)
    float m = aself;
    for (int i = rs + (lane >> 2); i < re; i += 16) {
        int s = csrc[i];
        float a = asrc[s * 4 + h] + adv;
        a = a > 0.f ? a : 0.2f * a;
        m = fmaxf(m, a);
    }
#pragma unroll
    for (int off = 4; off < 64; off <<= 1) m = fmaxf(m, __shfl_xor(m, off));

    // pass 2: denom
    float dsum = ((lane >> 2) == 0) ? expf(aself - m) : 0.f;
    for (int i = rs + (lane >> 2); i < re; i += 16) {
        int s = csrc[i];
        float a = asrc[s * 4 + h] + adv;
        a = a > 0.f ? a : 0.2f * a;
        dsum += expf(a - m);
    }
#pragma unroll
    for (int off = 4; off < 64; off <<= 1) dsum += __shfl_xor(dsum, off);
    const float inv = 1.f / dsum;

    // pass 3: gather-accumulate
    float acc[CPL];
#pragma unroll
    for (int r = 0; r < CPL; ++r) acc[r] = 0.f;

    {   // self loop
        float cv = expf(aself - m) * inv;          // valid for head h = lane&3
        const float* hp = H + (size_t)d * OUT;
#pragma unroll
        for (int r = 0; r < CPL; ++r) {
            int j = r * 64 + lane;
            int hj = (j < OUT) ? (j / C) : 0;
            float cf = __shfl(cv, hj);
            if (j < OUT) acc[r] += hp[j] * cf;
        }
    }
    for (int i = rs; i < re; ++i) {
        int s = csrc[i];
        float a = asrc[s * 4 + h] + adv;
        a = a > 0.f ? a : 0.2f * a;
        float cv = expf(a - m) * inv;
        const float* hp = H + (size_t)s * OUT;
#pragma unroll
        for (int r = 0; r < CPL; ++r) {
            int j = r * 64 + lane;
            int hj = (j < OUT) ? (j / C) : 0;
            float cf = __shfl(cv, hj);
            if (j < OUT) acc[r] += hp[j] * cf;
        }
    }

    // epilogue: bias / relu / emb copy, single coalesced write
#pragma unroll
    for (int r = 0; r < CPL; ++r) {
        int j = r * 64 + lane;
        if (j < OUT) {
            float v = acc[r];
            if (bias) v += bias[j];
            if (RELU) v = fmaxf(v, 0.f);
            Out[(size_t)d * OUT + j] = v;
            if (emb) emb[(size_t)d * OUT + j] = v;
        }
    }
}

// ---------------- layer-3 epilogue: head-mean + bias + log_softmax ----------------
__global__ void final_kernel(const float* __restrict__ B, const float* __restrict__ b3,
                             float* __restrict__ out, int n) {
    int node = blockIdx.x * blockDim.x + threadIdx.x;
    if (node >= n) return;
    float v[40];
    float mx = -1e30f;
#pragma unroll
    for (int c = 0; c < 40; ++c) {
        float s = 0.f;
        for (int h = 0; h < 4; ++h) s += B[(size_t)node * 160 + h * 40 + c];
        s = 0.25f * s + b3[c];
        v[c] = s;
        mx = fmaxf(mx, s);
    }
    float sum = 0.f;
#pragma unroll
    for (int c = 0; c < 40; ++c) sum += expf(v[c] - mx);
    float lg = mx + logf(sum);
#pragma unroll
    for (int c = 0; c < 40; ++c) out[(size_t)node * 40 + c] = v[c] - lg;
}

extern "C" void kernel_launch(void* const* d_in, const int* in_sizes, int n_in,
                              void* d_out, int out_size, void* d_ws, size_t ws_size,
                              hipStream_t stream) {
    const float* x   = (const float*)d_in[0];
    const int*   ei  = (const int*)d_in[1];
    const float* W1  = (const float*)d_in[2];
    const float* as1 = (const float*)d_in[3];
    const float* ad1 = (const float*)d_in[4];
    const float* b1  = (const float*)d_in[5];
    const float* W2  = (const float*)d_in[6];
    const float* as2 = (const float*)d_in[7];
    const float* ad2 = (const float*)d_in[8];
    const float* b2  = (const float*)d_in[9];
    const float* W3  = (const float*)d_in[10];
    const float* as3 = (const float*)d_in[11];
    const float* ad3 = (const float*)d_in[12];
    const float* b3  = (const float*)d_in[13];

    const int n = in_sizes[0] / 128;      // 50000
    const int E = in_sizes[1] / 2;        // 800000
    const int* src = ei;
    const int* dst = ei + E;

    float* ws = (float*)d_ws;
    float* A    = ws;                          // n*160
    float* B    = A + (size_t)n * 160;         // n*160
    float* asrc = B + (size_t)n * 160;         // n*4
    float* adst = asrc + (size_t)n * 4;        // n*4
    int* counts = (int*)(adst + (size_t)n * 4);  // n
    int* rowptr = counts + n;                    // n+1
    int* cursor = rowptr + n + 1;                // n
    int* csrc   = cursor + n;                    // E

    float* logits = (float*)d_out;               // n*40
    float* emb    = logits + (size_t)n * 40;     // n*128

    const int BT = 256;
    const int nb_nh   = (n * GHEADS + BT - 1) / BT;
    const int nb_edge = (E + BT - 1) / BT;
    const int nb_agg  = (n * 64 + BT - 1) / BT;  // one wave per node
    const int nb_g8   = (n + 7) / 8;

    // ---------------- CSR build (once; shared by all 3 layers) ----------------
    hipMemsetAsync(counts, 0, (size_t)n * sizeof(int), stream);
    hist_kernel<<<nb_edge, BT, 0, stream>>>(dst, E, counts);
    scan_kernel<<<1, 1024, 0, stream>>>(counts, rowptr, n);
    hipMemcpyAsync(cursor, rowptr, (size_t)n * sizeof(int), hipMemcpyDeviceToDevice, stream);
    place_kernel<<<nb_edge, BT, 0, stream>>>(src, dst, E, cursor, csrc);

    // ---------------- layer 1 ----------------
    gemm_kernel<128, 128><<<nb_g8, 128, 0, stream>>>(x, W1, A, n);
    attdot_kernel<32><<<nb_nh, BT, 0, stream>>>(A, as1, ad1, asrc, adst, n);
    agg_kernel<128, true><<<nb_agg, BT, 0, stream>>>(rowptr, csrc, asrc, adst, A, b1, B, nullptr, n);

    // ---------------- layer 2 ----------------
    gemm_kernel<128, 128><<<nb_g8, 128, 0, stream>>>(B, W2, A, n);
    attdot_kernel<32><<<nb_nh, BT, 0, stream>>>(A, as2, ad2, asrc, adst, n);
    agg_kernel<128, true><<<nb_agg, BT, 0, stream>>>(rowptr, csrc, asrc, adst, A, b2, B, emb, n);

    // ---------------- layer 3 ----------------
    gemm_kernel<160, 128><<<nb_g8, 160, 0, stream>>>(B, W3, A, n);
    attdot_kernel<40><<<nb_nh, BT, 0, stream>>>(A, as3, ad3, asrc, adst, n);
    agg_kernel<160, false><<<nb_agg, BT, 0, stream>>>(rowptr, csrc, asrc, adst, A, nullptr, B, nullptr, n);
    final_kernel<<<(n + 127) / 128, 128, 0, stream>>>(B, b3, logits, n);
}

// Round 3
// 516.303 us; speedup vs baseline: 3.1066x; 1.4122x over previous
//
#include <hip/hip_runtime.h>
#include <math.h>

#define GHEADS 4

__device__ __forceinline__ float b2f(ushort u) { return __uint_as_float(((unsigned)u) << 16); }
__device__ __forceinline__ ushort f2b(float f) {
    unsigned u = __float_as_uint(f);
    unsigned r = (u + 0x7fffu + ((u >> 16) & 1u)) >> 16;
    return (ushort)r;
}
__device__ __forceinline__ float lrelu(float a) { return a > 0.f ? a : 0.2f * a; }

// ---------------- GEMM: H16[n, OUT] = bf16( X[n, K] @ W[K, OUT] ) ----------------
template<int OUT, int K>
__global__ void __launch_bounds__(OUT) gemm_kernel(const float* __restrict__ X,
                                                   const float* __restrict__ W,
                                                   ushort* __restrict__ H16, int n) {
    __shared__ float xs[8][K];
    const int row0 = blockIdx.x * 8;
    const int tid = threadIdx.x;
    const int rows = (n - row0 < 8) ? (n - row0) : 8;
    for (int i = tid; i < rows * K; i += OUT) {
        int r = i / K, k = i % K;
        xs[r][k] = X[(size_t)(row0 + r) * K + k];
    }
    __syncthreads();
    float acc[8] = {0.f,0.f,0.f,0.f,0.f,0.f,0.f,0.f};
    for (int k = 0; k < K; ++k) {
        float w = W[k * OUT + tid];
#pragma unroll
        for (int r = 0; r < 8; ++r) acc[r] += xs[r][k] * w;
    }
    for (int r = 0; r < rows; ++r) H16[(size_t)(row0 + r) * OUT + tid] = f2b(acc[r]);
}

// ---------------- per-(node,head) attention dots (reads bf16 H) ----------------
template<int C>
__global__ void attdot_kernel(const ushort* __restrict__ H16,
                              const float* __restrict__ as_, const float* __restrict__ ad_,
                              float* __restrict__ asrc, float* __restrict__ adst, int n) {
    int i = blockIdx.x * blockDim.x + threadIdx.x;
    if (i >= n * GHEADS) return;
    int node = i >> 2, h = i & 3;
    const ushort2* hp = (const ushort2*)(H16 + (size_t)node * (GHEADS * C) + h * C);
    float s1 = 0.f, s2 = 0.f;
#pragma unroll 4
    for (int c2 = 0; c2 < C / 2; ++c2) {
        ushort2 v = hp[c2];
        float vx = b2f(v.x), vy = b2f(v.y);
        s1 += vx * as_[h * C + 2 * c2] + vy * as_[h * C + 2 * c2 + 1];
        s2 += vx * ad_[h * C + 2 * c2] + vy * ad_[h * C + 2 * c2 + 1];
    }
    asrc[i] = s1;
    adst[i] = s2;
}

// ---------------- CSR build ----------------
__global__ void hist_kernel(const int* __restrict__ dst, int E, int* __restrict__ counts) {
    int i = blockIdx.x * blockDim.x + threadIdx.x;
    if (i < E) atomicAdd(&counts[dst[i]], 1);
}

__global__ void __launch_bounds__(1024) scan_kernel(const int* __restrict__ counts,
                                                    int* __restrict__ rowptr, int n) {
    __shared__ int ps[1024];
    const int tid = threadIdx.x;
    const int chunk = (n + 1023) >> 10;
    const int b = tid * chunk;
    const int e = (b + chunk < n) ? b + chunk : n;
    int s = 0;
    for (int i = b; i < e; ++i) s += counts[i];
    ps[tid] = s;
    __syncthreads();
    for (int off = 1; off < 1024; off <<= 1) {
        int v = (tid >= off) ? ps[tid - off] : 0;
        __syncthreads();
        ps[tid] += v;
        __syncthreads();
    }
    int run = (tid == 0) ? 0 : ps[tid - 1];
    for (int i = b; i < e; ++i) { rowptr[i] = run; run += counts[i]; }
    if (tid == 1023) rowptr[n] = ps[1023];
}

__global__ void place_kernel(const int* __restrict__ src, const int* __restrict__ dst,
                             int E, int* __restrict__ cursor, int* __restrict__ csrc) {
    int i = blockIdx.x * blockDim.x + threadIdx.x;
    if (i < E) {
        int p = atomicAdd(&cursor[dst[i]], 1);
        csrc[p] = src[i];
    }
}

// ---------------- fused softmax + gather-aggregate: one wave per dst node ----------------
// sweep A: per-head max. sweep B: fused exp/denominator/gather (normalize at end).
template<int OUT, bool RELU>
__global__ void agg_kernel(const int* __restrict__ rowptr, const int* __restrict__ csrc,
                           const float* __restrict__ asrc, const float* __restrict__ adst,
                           const ushort* __restrict__ H16, const float* __restrict__ bias,
                           float* __restrict__ Out, float* __restrict__ emb, int n) {
    constexpr int C = OUT / GHEADS;
    constexpr bool RS2 = (OUT > 128);           // second channel step needed (OUT=160)
    int wid = (blockIdx.x * blockDim.x + threadIdx.x) >> 6;
    int lane = threadIdx.x & 63;
    if (wid >= n) return;
    const int d = wid;
    const int h4 = lane & 3;
    const int rs = rowptr[d], re = rowptr[d + 1];
    const int hs0 = (2 * lane) / C;             // head of my step-0 channel pair
    const bool act1 = RS2 && (lane < 16);       // step-1 lanes cover ch 128..159 (head 3)

    const float adv = adst[d * 4 + h4];
    const float aself = lrelu(asrc[d * 4 + h4] + adv);

    // ---- sweep A: per-head max (4-lane groups, 16 edges in parallel) ----
    float m = aself;
    for (int i = rs + (lane >> 2); i < re; i += 16) {
        int s = csrc[i];
        m = fmaxf(m, lrelu(asrc[(size_t)s * 4 + h4] + adv));
    }
#pragma unroll
    for (int off = 4; off < 64; off <<= 1) m = fmaxf(m, __shfl_xor(m, off));
    // m now per-head (identical on lanes sharing lane&3)

    // ---- sweep B: fused denom + gather ----
    float2 acc0 = make_float2(0.f, 0.f);
    float2 acc1 = make_float2(0.f, 0.f);
    float dsum = 0.f;

    {   // self loop
        float w = __expf(aself - m);
        dsum += w;
        const ushort2* rp = (const ushort2*)(H16 + (size_t)d * OUT);
        ushort2 v0 = rp[lane];
        float c0 = __shfl(w, hs0);
        acc0.x += c0 * b2f(v0.x); acc0.y += c0 * b2f(v0.y);
        if (RS2) {
            ushort2 v1 = {0, 0};
            if (act1) v1 = rp[64 + lane];
            float c1 = __shfl(w, 3);
            acc1.x += c1 * b2f(v1.x); acc1.y += c1 * b2f(v1.y);
        }
    }

    int i = rs;
    const int n4 = (re - rs) & ~3;
    for (; i < rs + n4; i += 4) {
        int s0 = csrc[i], s1 = csrc[i + 1], s2 = csrc[i + 2], s3 = csrc[i + 3];
        float r0 = asrc[(size_t)s0 * 4 + h4];
        float r1 = asrc[(size_t)s1 * 4 + h4];
        float r2 = asrc[(size_t)s2 * 4 + h4];
        float r3 = asrc[(size_t)s3 * 4 + h4];
        const ushort2* p0 = (const ushort2*)(H16 + (size_t)s0 * OUT);
        const ushort2* p1 = (const ushort2*)(H16 + (size_t)s1 * OUT);
        const ushort2* p2 = (const ushort2*)(H16 + (size_t)s2 * OUT);
        const ushort2* p3 = (const ushort2*)(H16 + (size_t)s3 * OUT);
        ushort2 v00 = p0[lane], v10 = p1[lane], v20 = p2[lane], v30 = p3[lane];
        ushort2 v01 = {0,0}, v11 = {0,0}, v21 = {0,0}, v31 = {0,0};
        if (act1) { v01 = p0[64 + lane]; v11 = p1[64 + lane]; v21 = p2[64 + lane]; v31 = p3[64 + lane]; }

        float w, c0, c1;
        w = __expf(lrelu(r0 + adv) - m); dsum += w;
        c0 = __shfl(w, hs0); acc0.x += c0 * b2f(v00.x); acc0.y += c0 * b2f(v00.y);
        if (RS2) { c1 = __shfl(w, 3); acc1.x += c1 * b2f(v01.x); acc1.y += c1 * b2f(v01.y); }
        w = __expf(lrelu(r1 + adv) - m); dsum += w;
        c0 = __shfl(w, hs0); acc0.x += c0 * b2f(v10.x); acc0.y += c0 * b2f(v10.y);
        if (RS2) { c1 = __shfl(w, 3); acc1.x += c1 * b2f(v11.x); acc1.y += c1 * b2f(v11.y); }
        w = __expf(lrelu(r2 + adv) - m); dsum += w;
        c0 = __shfl(w, hs0); acc0.x += c0 * b2f(v20.x); acc0.y += c0 * b2f(v20.y);
        if (RS2) { c1 = __shfl(w, 3); acc1.x += c1 * b2f(v21.x); acc1.y += c1 * b2f(v21.y); }
        w = __expf(lrelu(r3 + adv) - m); dsum += w;
        c0 = __shfl(w, hs0); acc0.x += c0 * b2f(v30.x); acc0.y += c0 * b2f(v30.y);
        if (RS2) { c1 = __shfl(w, 3); acc1.x += c1 * b2f(v31.x); acc1.y += c1 * b2f(v31.y); }
    }
    for (; i < re; ++i) {
        int s = csrc[i];
        float r = asrc[(size_t)s * 4 + h4];
        const ushort2* p = (const ushort2*)(H16 + (size_t)s * OUT);
        ushort2 v0 = p[lane];
        ushort2 v1 = {0, 0};
        if (act1) v1 = p[64 + lane];
        float w = __expf(lrelu(r + adv) - m); dsum += w;
        float c0 = __shfl(w, hs0);
        acc0.x += c0 * b2f(v0.x); acc0.y += c0 * b2f(v0.y);
        if (RS2) { float c1 = __shfl(w, 3); acc1.x += c1 * b2f(v1.x); acc1.y += c1 * b2f(v1.y); }
    }

    // ---- epilogue: normalize, bias, relu, write ----
    float inv0 = 1.f / __shfl(dsum, hs0);
    float ox = acc0.x * inv0, oy = acc0.y * inv0;
    int ch0 = 2 * lane;
    if (bias) { ox += bias[ch0]; oy += bias[ch0 + 1]; }
    if (RELU) { ox = fmaxf(ox, 0.f); oy = fmaxf(oy, 0.f); }
    float2* op = (float2*)(Out + (size_t)d * OUT);
    op[lane] = make_float2(ox, oy);
    if (emb) ((float2*)(emb + (size_t)d * OUT))[lane] = make_float2(ox, oy);
    if (RS2) {
        float inv1 = 1.f / __shfl(dsum, 3);
        if (act1) {
            float o1x = acc1.x * inv1, o1y = acc1.y * inv1;
            int ch1 = 128 + 2 * lane;
            if (bias) { o1x += bias[ch1]; o1y += bias[ch1 + 1]; }
            if (RELU) { o1x = fmaxf(o1x, 0.f); o1y = fmaxf(o1y, 0.f); }
            op[64 + lane] = make_float2(o1x, o1y);
        }
    }
}

// ---------------- layer-3 epilogue: head-mean + bias + log_softmax ----------------
__global__ void final_kernel(const float* __restrict__ B, const float* __restrict__ b3,
                             float* __restrict__ out, int n) {
    int node = blockIdx.x * blockDim.x + threadIdx.x;
    if (node >= n) return;
    float v[40];
    float mx = -1e30f;
#pragma unroll
    for (int c = 0; c < 40; ++c) {
        float s = 0.f;
        for (int h = 0; h < 4; ++h) s += B[(size_t)node * 160 + h * 40 + c];
        s = 0.25f * s + b3[c];
        v[c] = s;
        mx = fmaxf(mx, s);
    }
    float sum = 0.f;
#pragma unroll
    for (int c = 0; c < 40; ++c) sum += expf(v[c] - mx);
    float lg = mx + logf(sum);
#pragma unroll
    for (int c = 0; c < 40; ++c) out[(size_t)node * 40 + c] = v[c] - lg;
}

extern "C" void kernel_launch(void* const* d_in, const int* in_sizes, int n_in,
                              void* d_out, int out_size, void* d_ws, size_t ws_size,
                              hipStream_t stream) {
    const float* x   = (const float*)d_in[0];
    const int*   ei  = (const int*)d_in[1];
    const float* W1  = (const float*)d_in[2];
    const float* as1 = (const float*)d_in[3];
    const float* ad1 = (const float*)d_in[4];
    const float* b1  = (const float*)d_in[5];
    const float* W2  = (const float*)d_in[6];
    const float* as2 = (const float*)d_in[7];
    const float* ad2 = (const float*)d_in[8];
    const float* b2  = (const float*)d_in[9];
    const float* W3  = (const float*)d_in[10];
    const float* as3 = (const float*)d_in[11];
    const float* ad3 = (const float*)d_in[12];
    const float* b3  = (const float*)d_in[13];

    const int n = in_sizes[0] / 128;      // 50000
    const int E = in_sizes[1] / 2;        // 800000
    const int* src = ei;
    const int* dst = ei + E;

    float* ws = (float*)d_ws;
    float* B    = ws;                            // n*160 fp32 (layer io / final input)
    float* asrc = B + (size_t)n * 160;           // n*4
    float* adst = asrc + (size_t)n * 4;          // n*4
    int* counts = (int*)(adst + (size_t)n * 4);  // n
    int* rowptr = counts + n;                    // n+1
    int* cursor = rowptr + n + 1;                // n
    int* csrc   = cursor + n;                    // E
    ushort* A16 = (ushort*)(csrc + E);           // n*160 bf16 (GEMM output h)

    float* logits = (float*)d_out;               // n*40
    float* emb    = logits + (size_t)n * 40;     // n*128

    const int BT = 256;
    const int nb_nh   = (n * GHEADS + BT - 1) / BT;
    const int nb_edge = (E + BT - 1) / BT;
    const int nb_agg  = (n * 64 + BT - 1) / BT;  // one wave per node
    const int nb_g8   = (n + 7) / 8;

    // ---------------- CSR build (once; shared by all 3 layers) ----------------
    hipMemsetAsync(counts, 0, (size_t)n * sizeof(int), stream);
    hist_kernel<<<nb_edge, BT, 0, stream>>>(dst, E, counts);
    scan_kernel<<<1, 1024, 0, stream>>>(counts, rowptr, n);
    hipMemcpyAsync(cursor, rowptr, (size_t)n * sizeof(int), hipMemcpyDeviceToDevice, stream);
    place_kernel<<<nb_edge, BT, 0, stream>>>(src, dst, E, cursor, csrc);

    // ---------------- layer 1 ----------------
    gemm_kernel<128, 128><<<nb_g8, 128, 0, stream>>>(x, W1, A16, n);
    attdot_kernel<32><<<nb_nh, BT, 0, stream>>>(A16, as1, ad1, asrc, adst, n);
    agg_kernel<128, true><<<nb_agg, BT, 0, stream>>>(rowptr, csrc, asrc, adst, A16, b1, B, nullptr, n);

    // ---------------- layer 2 ----------------
    gemm_kernel<128, 128><<<nb_g8, 128, 0, stream>>>(B, W2, A16, n);
    attdot_kernel<32><<<nb_nh, BT, 0, stream>>>(A16, as2, ad2, asrc, adst, n);
    agg_kernel<128, true><<<nb_agg, BT, 0, stream>>>(rowptr, csrc, asrc, adst, A16, b2, B, emb, n);

    // ---------------- layer 3 ----------------
    gemm_kernel<160, 128><<<nb_g8, 160, 0, stream>>>(B, W3, A16, n);
    attdot_kernel<40><<<nb_nh, BT, 0, stream>>>(A16, as3, ad3, asrc, adst, n);
    agg_kernel<160, false><<<nb_agg, BT, 0, stream>>>(rowptr, csrc, asrc, adst, A16, nullptr, B, nullptr, n);
    final_kernel<<<(n + 127) / 128, 128, 0, stream>>>(B, b3, logits, n);
}

// Round 4
// 435.659 us; speedup vs baseline: 3.6817x; 1.1851x over previous
//
#include <hip/hip_runtime.h>
#include <math.h>

#define GHEADS 4

__device__ __forceinline__ float b2f(ushort u) { return __uint_as_float(((unsigned)u) << 16); }
__device__ __forceinline__ ushort f2b(float f) {
    unsigned u = __float_as_uint(f);
    unsigned r = (u + 0x7fffu + ((u >> 16) & 1u)) >> 16;
    return (ushort)r;
}
__device__ __forceinline__ float lrelu(float a) { return a > 0.f ? a : 0.2f * a; }

// ---------------- GEMM: H16[n, OUT] = bf16( X[n, K] @ W[K, OUT] ) ----------------
template<int OUT, int K>
__global__ void __launch_bounds__(OUT) gemm_kernel(const float* __restrict__ X,
                                                   const float* __restrict__ W,
                                                   ushort* __restrict__ H16, int n) {
    __shared__ float xs[8][K];
    const int row0 = blockIdx.x * 8;
    const int tid = threadIdx.x;
    const int rows = (n - row0 < 8) ? (n - row0) : 8;
    for (int i = tid; i < rows * K; i += OUT) {
        int r = i / K, k = i % K;
        xs[r][k] = X[(size_t)(row0 + r) * K + k];
    }
    __syncthreads();
    float acc[8] = {0.f,0.f,0.f,0.f,0.f,0.f,0.f,0.f};
    for (int k = 0; k < K; ++k) {
        float w = W[k * OUT + tid];
#pragma unroll
        for (int r = 0; r < 8; ++r) acc[r] += xs[r][k] * w;
    }
    for (int r = 0; r < rows; ++r) H16[(size_t)(row0 + r) * OUT + tid] = f2b(acc[r]);
}

// ---------------- per-(node,head) attention dots (reads bf16 H) ----------------
template<int C>
__global__ void attdot_kernel(const ushort* __restrict__ H16,
                              const float* __restrict__ as_, const float* __restrict__ ad_,
                              float* __restrict__ asrc, float* __restrict__ adst, int n) {
    int i = blockIdx.x * blockDim.x + threadIdx.x;
    if (i >= n * GHEADS) return;
    int node = i >> 2, h = i & 3;
    const ushort2* hp = (const ushort2*)(H16 + (size_t)node * (GHEADS * C) + h * C);
    float s1 = 0.f, s2 = 0.f;
#pragma unroll 4
    for (int c2 = 0; c2 < C / 2; ++c2) {
        ushort2 v = hp[c2];
        float vx = b2f(v.x), vy = b2f(v.y);
        s1 += vx * as_[h * C + 2 * c2] + vy * as_[h * C + 2 * c2 + 1];
        s2 += vx * ad_[h * C + 2 * c2] + vy * ad_[h * C + 2 * c2 + 1];
    }
    asrc[i] = s1;
    adst[i] = s2;
}

// ---------------- CSR build ----------------
__global__ void hist_kernel(const int* __restrict__ dst, int E, int* __restrict__ counts) {
    int i = blockIdx.x * blockDim.x + threadIdx.x;
    if (i < E) atomicAdd(&counts[dst[i]], 1);
}

// k1: per-block (256-elem) sums
__global__ void __launch_bounds__(256) bsum_kernel(const int* __restrict__ counts,
                                                   int* __restrict__ bsum, int n) {
    int i = blockIdx.x * 256 + threadIdx.x;
    int v = (i < n) ? counts[i] : 0;
#pragma unroll
    for (int off = 1; off < 64; off <<= 1) v += __shfl_xor(v, off);
    __shared__ int ws_[4];
    if ((threadIdx.x & 63) == 0) ws_[threadIdx.x >> 6] = v;
    __syncthreads();
    if (threadIdx.x == 0) bsum[blockIdx.x] = ws_[0] + ws_[1] + ws_[2] + ws_[3];
}

// k2: single block exclusive scan of bsum[nb] (nb <= 1024), in place
__global__ void __launch_bounds__(1024) bscan_kernel(int* __restrict__ bsum, int nb) {
    __shared__ int tmp[1024];
    int tid = threadIdx.x;
    int v = (tid < nb) ? bsum[tid] : 0;
    tmp[tid] = v;
    __syncthreads();
    for (int off = 1; off < 1024; off <<= 1) {
        int t = (tid >= off) ? tmp[tid - off] : 0;
        __syncthreads();
        tmp[tid] += t;
        __syncthreads();
    }
    if (tid < nb) bsum[tid] = tmp[tid] - v;
}

// k3: local scan + block offset -> rowptr (exclusive); also rowptr[n] = E
__global__ void __launch_bounds__(256) rowptr_kernel(const int* __restrict__ counts,
                                                     const int* __restrict__ bsum,
                                                     int* __restrict__ rowptr, int n, int E) {
    int i = blockIdx.x * 256 + threadIdx.x;
    int lane = threadIdx.x & 63, wid = threadIdx.x >> 6;
    int v = (i < n) ? counts[i] : 0;
    int x = v;
#pragma unroll
    for (int off = 1; off < 64; off <<= 1) {
        int t = __shfl_up(x, off);
        if (lane >= off) x += t;
    }
    __shared__ int wsum[4];
    if (lane == 63) wsum[wid] = x;
    __syncthreads();
    int woff = 0;
    for (int w = 0; w < 4; ++w) if (w < wid) woff += wsum[w];
    int excl = bsum[blockIdx.x] + woff + (x - v);
    if (i < n) rowptr[i] = excl;
    if (i == n - 1) rowptr[n] = E;
}

__global__ void place_kernel(const int* __restrict__ src, const int* __restrict__ dst,
                             int E, int* __restrict__ cursor, int* __restrict__ csrc) {
    int i = blockIdx.x * blockDim.x + threadIdx.x;
    if (i < E) {
        int p = atomicAdd(&cursor[dst[i]], 1);
        csrc[p] = src[i];
    }
}

// ---------------- fused softmax + gather-aggregate: one wave per dst node ----------------
// single sweep: accumulate sum(exp*h) and sum(exp); normalize at end (no max needed:
// |alpha| <~ 12 << 88, fp32 exp cannot overflow; identical after normalization).
template<int OUT, bool RELU>
__global__ void agg_kernel(const int* __restrict__ rowptr, const int* __restrict__ csrc,
                           const float* __restrict__ asrc, const float* __restrict__ adst,
                           const ushort* __restrict__ H16, const float* __restrict__ bias,
                           float* __restrict__ Out, float* __restrict__ emb, int n) {
    constexpr int C = OUT / GHEADS;
    constexpr bool RS2 = (OUT > 128);           // second channel step needed (OUT=160)
    constexpr int UN = 8;
    int wid = (blockIdx.x * blockDim.x + threadIdx.x) >> 6;
    int lane = threadIdx.x & 63;
    if (wid >= n) return;
    const int d = wid;
    const int h4 = lane & 3;
    const int rs = rowptr[d], re = rowptr[d + 1];
    const int hs0 = (2 * lane) / C;             // head of my step-0 channel pair
    const bool act1 = RS2 && (lane < 16);       // step-1 lanes cover ch 128..159 (head 3)

    const float adv = adst[d * 4 + h4];
    const float aself = lrelu(asrc[d * 4 + h4] + adv);

    float2 acc0 = make_float2(0.f, 0.f);
    float2 acc1 = make_float2(0.f, 0.f);
    float dsum = 0.f;

    {   // self loop
        float w = __expf(aself);
        dsum += w;
        const ushort2* rp = (const ushort2*)(H16 + (size_t)d * OUT);
        ushort2 v0 = rp[lane];
        float c0 = __shfl(w, hs0);
        acc0.x += c0 * b2f(v0.x); acc0.y += c0 * b2f(v0.y);
        if (RS2) {
            ushort2 v1 = {0, 0};
            if (act1) v1 = rp[64 + lane];
            float c1 = __shfl(w, 3);
            acc1.x += c1 * b2f(v1.x); acc1.y += c1 * b2f(v1.y);
        }
    }

    int i = rs;
    const int nU = (re - rs) / UN * UN;
    for (; i < rs + nU; i += UN) {
        int s[UN];
        float r[UN];
        ushort2 v0[UN], v1[UN];
#pragma unroll
        for (int u = 0; u < UN; ++u) s[u] = csrc[i + u];
#pragma unroll
        for (int u = 0; u < UN; ++u) r[u] = asrc[(size_t)s[u] * 4 + h4];
#pragma unroll
        for (int u = 0; u < UN; ++u) {
            const ushort2* p = (const ushort2*)(H16 + (size_t)s[u] * OUT);
            v0[u] = p[lane];
            if (RS2) { v1[u] = act1 ? p[64 + lane] : make_ushort2(0, 0); }
        }
#pragma unroll
        for (int u = 0; u < UN; ++u) {
            float w = __expf(lrelu(r[u] + adv));
            dsum += w;
            float c0 = __shfl(w, hs0);
            acc0.x += c0 * b2f(v0[u].x); acc0.y += c0 * b2f(v0[u].y);
            if (RS2) {
                float c1 = __shfl(w, 3);
                acc1.x += c1 * b2f(v1[u].x); acc1.y += c1 * b2f(v1[u].y);
            }
        }
    }
    for (; i < re; ++i) {
        int s = csrc[i];
        float r = asrc[(size_t)s * 4 + h4];
        const ushort2* p = (const ushort2*)(H16 + (size_t)s * OUT);
        ushort2 v0 = p[lane];
        ushort2 v1 = {0, 0};
        if (act1) v1 = p[64 + lane];
        float w = __expf(lrelu(r + adv));
        dsum += w;
        float c0 = __shfl(w, hs0);
        acc0.x += c0 * b2f(v0.x); acc0.y += c0 * b2f(v0.y);
        if (RS2) { float c1 = __shfl(w, 3); acc1.x += c1 * b2f(v1.x); acc1.y += c1 * b2f(v1.y); }
    }

    // ---- epilogue: normalize, bias, relu, write ----
    float inv0 = 1.f / __shfl(dsum, hs0);
    float ox = acc0.x * inv0, oy = acc0.y * inv0;
    int ch0 = 2 * lane;
    if (bias) { ox += bias[ch0]; oy += bias[ch0 + 1]; }
    if (RELU) { ox = fmaxf(ox, 0.f); oy = fmaxf(oy, 0.f); }
    float2* op = (float2*)(Out + (size_t)d * OUT);
    op[lane] = make_float2(ox, oy);
    if (emb) ((float2*)(emb + (size_t)d * OUT))[lane] = make_float2(ox, oy);
    if (RS2) {
        float inv1 = 1.f / __shfl(dsum, 3);
        if (act1) {
            float o1x = acc1.x * inv1, o1y = acc1.y * inv1;
            int ch1 = 128 + 2 * lane;
            if (bias) { o1x += bias[ch1]; o1y += bias[ch1 + 1]; }
            if (RELU) { o1x = fmaxf(o1x, 0.f); o1y = fmaxf(o1y, 0.f); }
            op[64 + lane] = make_float2(o1x, o1y);
        }
    }
}

// ---------------- layer-3 epilogue: head-mean + bias + log_softmax ----------------
__global__ void final_kernel(const float* __restrict__ B, const float* __restrict__ b3,
                             float* __restrict__ out, int n) {
    int node = blockIdx.x * blockDim.x + threadIdx.x;
    if (node >= n) return;
    float v[40];
    float mx = -1e30f;
#pragma unroll
    for (int c = 0; c < 40; ++c) {
        float s = 0.f;
        for (int h = 0; h < 4; ++h) s += B[(size_t)node * 160 + h * 40 + c];
        s = 0.25f * s + b3[c];
        v[c] = s;
        mx = fmaxf(mx, s);
    }
    float sum = 0.f;
#pragma unroll
    for (int c = 0; c < 40; ++c) sum += expf(v[c] - mx);
    float lg = mx + logf(sum);
#pragma unroll
    for (int c = 0; c < 40; ++c) out[(size_t)node * 40 + c] = v[c] - lg;
}

extern "C" void kernel_launch(void* const* d_in, const int* in_sizes, int n_in,
                              void* d_out, int out_size, void* d_ws, size_t ws_size,
                              hipStream_t stream) {
    const float* x   = (const float*)d_in[0];
    const int*   ei  = (const int*)d_in[1];
    const float* W1  = (const float*)d_in[2];
    const float* as1 = (const float*)d_in[3];
    const float* ad1 = (const float*)d_in[4];
    const float* b1  = (const float*)d_in[5];
    const float* W2  = (const float*)d_in[6];
    const float* as2 = (const float*)d_in[7];
    const float* ad2 = (const float*)d_in[8];
    const float* b2  = (const float*)d_in[9];
    const float* W3  = (const float*)d_in[10];
    const float* as3 = (const float*)d_in[11];
    const float* ad3 = (const float*)d_in[12];
    const float* b3  = (const float*)d_in[13];

    const int n = in_sizes[0] / 128;      // 50000
    const int E = in_sizes[1] / 2;        // 800000
    const int* src = ei;
    const int* dst = ei + E;

    float* ws = (float*)d_ws;
    float* B    = ws;                            // n*160 fp32 (layer io / final input)
    float* asrc = B + (size_t)n * 160;           // n*4
    float* adst = asrc + (size_t)n * 4;          // n*4
    int* counts = (int*)(adst + (size_t)n * 4);  // n
    int* rowptr = counts + n;                    // n+1
    int* cursor = rowptr + n + 1;                // n
    int* bsum   = cursor + n;                    // 1024
    int* csrc   = bsum + 1024;                   // E
    ushort* A16 = (ushort*)(csrc + E);           // n*160 bf16 (GEMM output h)

    float* logits = (float*)d_out;               // n*40
    float* emb    = logits + (size_t)n * 40;     // n*128

    const int BT = 256;
    const int nb_nh   = (n * GHEADS + BT - 1) / BT;
    const int nb_edge = (E + BT - 1) / BT;
    const int nb_agg  = (n * 64 + BT - 1) / BT;  // one wave per node
    const int nb_g8   = (n + 7) / 8;
    const int nb_scan = (n + 255) / 256;         // 196

    // ---------------- CSR build (once; shared by all 3 layers) ----------------
    hipMemsetAsync(counts, 0, (size_t)n * sizeof(int), stream);
    hist_kernel<<<nb_edge, BT, 0, stream>>>(dst, E, counts);
    bsum_kernel<<<nb_scan, 256, 0, stream>>>(counts, bsum, n);
    bscan_kernel<<<1, 1024, 0, stream>>>(bsum, nb_scan);
    rowptr_kernel<<<nb_scan, 256, 0, stream>>>(counts, bsum, rowptr, n, E);
    hipMemcpyAsync(cursor, rowptr, (size_t)n * sizeof(int), hipMemcpyDeviceToDevice, stream);
    place_kernel<<<nb_edge, BT, 0, stream>>>(src, dst, E, cursor, csrc);

    // ---------------- layer 1 ----------------
    gemm_kernel<128, 128><<<nb_g8, 128, 0, stream>>>(x, W1, A16, n);
    attdot_kernel<32><<<nb_nh, BT, 0, stream>>>(A16, as1, ad1, asrc, adst, n);
    agg_kernel<128, true><<<nb_agg, BT, 0, stream>>>(rowptr, csrc, asrc, adst, A16, b1, B, nullptr, n);

    // ---------------- layer 2 ----------------
    gemm_kernel<128, 128><<<nb_g8, 128, 0, stream>>>(B, W2, A16, n);
    attdot_kernel<32><<<nb_nh, BT, 0, stream>>>(A16, as2, ad2, asrc, adst, n);
    agg_kernel<128, true><<<nb_agg, BT, 0, stream>>>(rowptr, csrc, asrc, adst, A16, b2, B, emb, n);

    // ---------------- layer 3 ----------------
    gemm_kernel<160, 128><<<nb_g8, 160, 0, stream>>>(B, W3, A16, n);
    attdot_kernel<40><<<nb_nh, BT, 0, stream>>>(A16, as3, ad3, asrc, adst, n);
    agg_kernel<160, false><<<nb_agg, BT, 0, stream>>>(rowptr, csrc, asrc, adst, A16, nullptr, B, nullptr, n);
    final_kernel<<<(n + 127) / 128, 128, 0, stream>>>(B, b3, logits, n);
}

// Round 5
// 366.426 us; speedup vs baseline: 4.3773x; 1.1889x over previous
//
#include <hip/hip_runtime.h>
#include <math.h>

#define GHEADS 4
typedef __attribute__((ext_vector_type(8))) short bf16x8;
typedef __attribute__((ext_vector_type(4))) float f32x4;

__device__ __forceinline__ float b2f(ushort u) { return __uint_as_float(((unsigned)u) << 16); }
__device__ __forceinline__ ushort f2b(float f) {
    unsigned u = __float_as_uint(f);
    unsigned r = (u + 0x7fffu + ((u >> 16) & 1u)) >> 16;
    return (ushort)r;
}
__device__ __forceinline__ float lrelu(float a) { return a > 0.f ? a : 0.2f * a; }

// ---------------- fp32 -> bf16 bulk convert (x input) ----------------
__global__ void cvtx_kernel(const float* __restrict__ X, ushort* __restrict__ X16, int total4) {
    int i = blockIdx.x * blockDim.x + threadIdx.x;
    if (i >= total4) return;
    float4 v = ((const float4*)X)[i];
    uint2 o;
    o.x = (uint)f2b(v.x) | ((uint)f2b(v.y) << 16);
    o.y = (uint)f2b(v.z) | ((uint)f2b(v.w) << 16);
    ((uint2*)X16)[i] = o;
}

// ---------------- W[K][N] fp32 -> Wt16[N][K] bf16 (transpose) ----------------
__global__ void cvtw_kernel(const float* __restrict__ W, ushort* __restrict__ Wt, int K, int N) {
    int i = blockIdx.x * blockDim.x + threadIdx.x;
    if (i >= N * K) return;
    int nn = i / K, k = i - nn * K;
    Wt[i] = f2b(W[k * N + nn]);
}

// ---------------- MFMA GEMM: H16[np, N] = X16[np,128] @ W (Wt16[N][128]) ----------------
// block: 32 rows x N cols; wave w owns cols [w*32, w*32+32); 2x2 fragments of 16x16, K=128.
template<int NW>
__global__ void __launch_bounds__(NW * 64) mgemm_kernel(const ushort* __restrict__ X16,
                                                        const ushort* __restrict__ Wt16,
                                                        ushort* __restrict__ H16, int n) {
    constexpr int N = NW * 32;
    const int wave = threadIdx.x >> 6;
    const int lane = threadIdx.x & 63;
    const int row0 = blockIdx.x * 32;
    const int col0 = wave * 32;
    const int lr = lane & 15;
    const int lk = (lane >> 4) << 3;

    const ushort* Xp = X16 + (size_t)(row0 + lr) * 128 + lk;
    const ushort* Wp = Wt16 + (size_t)(col0 + lr) * 128 + lk;

    f32x4 acc00 = {0.f,0.f,0.f,0.f}, acc01 = {0.f,0.f,0.f,0.f};
    f32x4 acc10 = {0.f,0.f,0.f,0.f}, acc11 = {0.f,0.f,0.f,0.f};
#pragma unroll
    for (int kk = 0; kk < 4; ++kk) {
        bf16x8 a0 = *(const bf16x8*)(Xp + kk * 32);
        bf16x8 a1 = *(const bf16x8*)(Xp + 16 * 128 + kk * 32);
        bf16x8 b0 = *(const bf16x8*)(Wp + kk * 32);
        bf16x8 b1 = *(const bf16x8*)(Wp + 16 * 128 + kk * 32);
        acc00 = __builtin_amdgcn_mfma_f32_16x16x32_bf16(a0, b0, acc00, 0, 0, 0);
        acc10 = __builtin_amdgcn_mfma_f32_16x16x32_bf16(a1, b0, acc10, 0, 0, 0);
        acc01 = __builtin_amdgcn_mfma_f32_16x16x32_bf16(a0, b1, acc01, 0, 0, 0);
        acc11 = __builtin_amdgcn_mfma_f32_16x16x32_bf16(a1, b1, acc11, 0, 0, 0);
    }
    // C/D layout: col = lane&15, row = (lane>>4)*4 + reg
    const int rbase = (lane >> 4) * 4;
#pragma unroll
    for (int r = 0; r < 4; ++r) {
        int row = row0 + rbase + r;
        if (row < n) {
            H16[(size_t)row * N + col0 + lr]      = f2b(acc00[r]);
            H16[(size_t)row * N + col0 + 16 + lr] = f2b(acc01[r]);
        }
        int row2 = row + 16;
        if (row2 < n) {
            H16[(size_t)row2 * N + col0 + lr]      = f2b(acc10[r]);
            H16[(size_t)row2 * N + col0 + 16 + lr] = f2b(acc11[r]);
        }
    }
}

// ---------------- per-(node,head) attention dots (reads bf16 H) ----------------
template<int C>
__global__ void attdot_kernel(const ushort* __restrict__ H16,
                              const float* __restrict__ as_, const float* __restrict__ ad_,
                              float* __restrict__ asrc, float* __restrict__ adst, int n) {
    int i = blockIdx.x * blockDim.x + threadIdx.x;
    if (i >= n * GHEADS) return;
    int node = i >> 2, h = i & 3;
    const ushort2* hp = (const ushort2*)(H16 + (size_t)node * (GHEADS * C) + h * C);
    float s1 = 0.f, s2 = 0.f;
#pragma unroll 4
    for (int c2 = 0; c2 < C / 2; ++c2) {
        ushort2 v = hp[c2];
        float vx = b2f(v.x), vy = b2f(v.y);
        s1 += vx * as_[h * C + 2 * c2] + vy * as_[h * C + 2 * c2 + 1];
        s2 += vx * ad_[h * C + 2 * c2] + vy * ad_[h * C + 2 * c2 + 1];
    }
    asrc[i] = s1;
    adst[i] = s2;
}

// ---------------- CSR build ----------------
__global__ void hist_kernel(const int* __restrict__ dst, int E, int* __restrict__ counts) {
    int i = blockIdx.x * blockDim.x + threadIdx.x;
    if (i < E) atomicAdd(&counts[dst[i]], 1);
}

__global__ void __launch_bounds__(256) bsum_kernel(const int* __restrict__ counts,
                                                   int* __restrict__ bsum, int n) {
    int i = blockIdx.x * 256 + threadIdx.x;
    int v = (i < n) ? counts[i] : 0;
#pragma unroll
    for (int off = 1; off < 64; off <<= 1) v += __shfl_xor(v, off);
    __shared__ int ws_[4];
    if ((threadIdx.x & 63) == 0) ws_[threadIdx.x >> 6] = v;
    __syncthreads();
    if (threadIdx.x == 0) bsum[blockIdx.x] = ws_[0] + ws_[1] + ws_[2] + ws_[3];
}

__global__ void __launch_bounds__(1024) bscan_kernel(int* __restrict__ bsum, int nb) {
    __shared__ int tmp[1024];
    int tid = threadIdx.x;
    int v = (tid < nb) ? bsum[tid] : 0;
    tmp[tid] = v;
    __syncthreads();
    for (int off = 1; off < 1024; off <<= 1) {
        int t = (tid >= off) ? tmp[tid - off] : 0;
        __syncthreads();
        tmp[tid] += t;
        __syncthreads();
    }
    if (tid < nb) bsum[tid] = tmp[tid] - v;
}

__global__ void __launch_bounds__(256) rowptr_kernel(const int* __restrict__ counts,
                                                     const int* __restrict__ bsum,
                                                     int* __restrict__ rowptr, int n, int E) {
    int i = blockIdx.x * 256 + threadIdx.x;
    int lane = threadIdx.x & 63, wid = threadIdx.x >> 6;
    int v = (i < n) ? counts[i] : 0;
    int x = v;
#pragma unroll
    for (int off = 1; off < 64; off <<= 1) {
        int t = __shfl_up(x, off);
        if (lane >= off) x += t;
    }
    __shared__ int wsum[4];
    if (lane == 63) wsum[wid] = x;
    __syncthreads();
    int woff = 0;
    for (int w = 0; w < 4; ++w) if (w < wid) woff += wsum[w];
    int excl = bsum[blockIdx.x] + woff + (x - v);
    if (i < n) rowptr[i] = excl;
    if (i == n - 1) rowptr[n] = E;
}

__global__ void place_kernel(const int* __restrict__ src, const int* __restrict__ dst,
                             int E, int* __restrict__ cursor, int* __restrict__ csrc) {
    int i = blockIdx.x * blockDim.x + threadIdx.x;
    if (i < E) {
        int p = atomicAdd(&cursor[dst[i]], 1);
        csrc[p] = src[i];
    }
}

// ---------------- fused softmax + gather-aggregate: one wave per dst node ----------------
// single sweep (no max: |alpha| <~ 12 << 88, identical after normalization).
// BF16OUT: write bf16 to outv (next GEMM input); else fp32.
template<int OUT, bool RELU, bool BF16OUT>
__global__ void agg_kernel(const int* __restrict__ rowptr, const int* __restrict__ csrc,
                           const float* __restrict__ asrc, const float* __restrict__ adst,
                           const ushort* __restrict__ H16, const float* __restrict__ bias,
                           void* __restrict__ outv, float* __restrict__ emb, int n) {
    constexpr int C = OUT / GHEADS;
    constexpr bool RS2 = (OUT > 128);
    constexpr int UN = 8;
    int wid = (blockIdx.x * blockDim.x + threadIdx.x) >> 6;
    int lane = threadIdx.x & 63;
    if (wid >= n) return;
    const int d = wid;
    const int h4 = lane & 3;
    const int rs = rowptr[d], re = rowptr[d + 1];
    const int hs0 = (2 * lane) / C;
    const bool act1 = RS2 && (lane < 16);

    const float adv = adst[d * 4 + h4];
    const float aself = lrelu(asrc[d * 4 + h4] + adv);

    float2 acc0 = make_float2(0.f, 0.f);
    float2 acc1 = make_float2(0.f, 0.f);
    float dsum = 0.f;

    {   // self loop
        float w = __expf(aself);
        dsum += w;
        const ushort2* rp = (const ushort2*)(H16 + (size_t)d * OUT);
        ushort2 v0 = rp[lane];
        float c0 = __shfl(w, hs0);
        acc0.x += c0 * b2f(v0.x); acc0.y += c0 * b2f(v0.y);
        if (RS2) {
            ushort2 v1 = {0, 0};
            if (act1) v1 = rp[64 + lane];
            float c1 = __shfl(w, 3);
            acc1.x += c1 * b2f(v1.x); acc1.y += c1 * b2f(v1.y);
        }
    }

    int i = rs;
    const int nU = (re - rs) / UN * UN;
    for (; i < rs + nU; i += UN) {
        int s[UN];
        float r[UN];
        ushort2 v0[UN], v1[UN];
#pragma unroll
        for (int u = 0; u < UN; ++u) s[u] = csrc[i + u];
#pragma unroll
        for (int u = 0; u < UN; ++u) r[u] = asrc[(size_t)s[u] * 4 + h4];
#pragma unroll
        for (int u = 0; u < UN; ++u) {
            const ushort2* p = (const ushort2*)(H16 + (size_t)s[u] * OUT);
            v0[u] = p[lane];
            if (RS2) { v1[u] = act1 ? p[64 + lane] : make_ushort2(0, 0); }
        }
#pragma unroll
        for (int u = 0; u < UN; ++u) {
            float w = __expf(lrelu(r[u] + adv));
            dsum += w;
            float c0 = __shfl(w, hs0);
            acc0.x += c0 * b2f(v0[u].x); acc0.y += c0 * b2f(v0[u].y);
            if (RS2) {
                float c1 = __shfl(w, 3);
                acc1.x += c1 * b2f(v1[u].x); acc1.y += c1 * b2f(v1[u].y);
            }
        }
    }
    for (; i < re; ++i) {
        int s = csrc[i];
        float r = asrc[(size_t)s * 4 + h4];
        const ushort2* p = (const ushort2*)(H16 + (size_t)s * OUT);
        ushort2 v0 = p[lane];
        ushort2 v1 = {0, 0};
        if (act1) v1 = p[64 + lane];
        float w = __expf(lrelu(r + adv));
        dsum += w;
        float c0 = __shfl(w, hs0);
        acc0.x += c0 * b2f(v0.x); acc0.y += c0 * b2f(v0.y);
        if (RS2) { float c1 = __shfl(w, 3); acc1.x += c1 * b2f(v1.x); acc1.y += c1 * b2f(v1.y); }
    }

    // ---- epilogue ----
    float inv0 = 1.f / __shfl(dsum, hs0);
    float ox = acc0.x * inv0, oy = acc0.y * inv0;
    int ch0 = 2 * lane;
    if (bias) { ox += bias[ch0]; oy += bias[ch0 + 1]; }
    if (RELU) { ox = fmaxf(ox, 0.f); oy = fmaxf(oy, 0.f); }
    if (BF16OUT) {
        unsigned o = (unsigned)f2b(ox) | ((unsigned)f2b(oy) << 16);
        ((unsigned*)outv)[(size_t)d * (OUT / 2) + lane] = o;
        if (emb) ((float2*)(emb + (size_t)d * OUT))[lane] = make_float2(ox, oy);
    } else {
        float2* op = (float2*)((float*)outv + (size_t)d * OUT);
        op[lane] = make_float2(ox, oy);
        if (RS2) {
            float inv1 = 1.f / __shfl(dsum, 3);
            if (act1) {
                float o1x = acc1.x * inv1, o1y = acc1.y * inv1;
                int ch1 = 128 + 2 * lane;
                if (bias) { o1x += bias[ch1]; o1y += bias[ch1 + 1]; }
                if (RELU) { o1x = fmaxf(o1x, 0.f); o1y = fmaxf(o1y, 0.f); }
                op[64 + lane] = make_float2(o1x, o1y);
            }
        }
    }
}

// ---------------- layer-3 epilogue: head-mean + bias + log_softmax ----------------
__global__ void final_kernel(const float* __restrict__ B, const float* __restrict__ b3,
                             float* __restrict__ out, int n) {
    int node = blockIdx.x * blockDim.x + threadIdx.x;
    if (node >= n) return;
    float v[40];
    float mx = -1e30f;
#pragma unroll
    for (int c = 0; c < 40; ++c) {
        float s = 0.f;
        for (int h = 0; h < 4; ++h) s += B[(size_t)node * 160 + h * 40 + c];
        s = 0.25f * s + b3[c];
        v[c] = s;
        mx = fmaxf(mx, s);
    }
    float sum = 0.f;
#pragma unroll
    for (int c = 0; c < 40; ++c) sum += expf(v[c] - mx);
    float lg = mx + logf(sum);
#pragma unroll
    for (int c = 0; c < 40; ++c) out[(size_t)node * 40 + c] = v[c] - lg;
}

extern "C" void kernel_launch(void* const* d_in, const int* in_sizes, int n_in,
                              void* d_out, int out_size, void* d_ws, size_t ws_size,
                              hipStream_t stream) {
    const float* x   = (const float*)d_in[0];
    const int*   ei  = (const int*)d_in[1];
    const float* W1  = (const float*)d_in[2];
    const float* as1 = (const float*)d_in[3];
    const float* ad1 = (const float*)d_in[4];
    const float* b1  = (const float*)d_in[5];
    const float* W2  = (const float*)d_in[6];
    const float* as2 = (const float*)d_in[7];
    const float* ad2 = (const float*)d_in[8];
    const float* b2  = (const float*)d_in[9];
    const float* W3  = (const float*)d_in[10];
    const float* as3 = (const float*)d_in[11];
    const float* ad3 = (const float*)d_in[12];
    const float* b3  = (const float*)d_in[13];

    const int n = in_sizes[0] / 128;      // 50000
    const int E = in_sizes[1] / 2;        // 800000
    const int np = (n + 31) & ~31;        // padded rows for guard-free MFMA loads
    const int* src = ei;
    const int* dst = ei + E;

    // workspace carve (64B aligned)
    char* p = (char*)d_ws;
    auto alloc = [&](size_t bytes) { char* q = p; p += (bytes + 63) & ~(size_t)63; return q; };
    float*  B      = (float*)alloc((size_t)n * 160 * 4);
    float*  asrc   = (float*)alloc((size_t)n * 4 * 4);
    float*  adst   = (float*)alloc((size_t)n * 4 * 4);
    int*    counts = (int*)alloc((size_t)n * 4);
    int*    rowptr = (int*)alloc((size_t)(n + 1) * 4);
    int*    cursor = (int*)alloc((size_t)n * 4);
    int*    bsum   = (int*)alloc(1024 * 4);
    int*    csrc   = (int*)alloc((size_t)E * 4);
    ushort* X16    = (ushort*)alloc((size_t)np * 128 * 2);
    ushort* H16    = (ushort*)alloc((size_t)np * 160 * 2);
    ushort* Wt16   = (ushort*)alloc((size_t)160 * 128 * 2);

    float* logits = (float*)d_out;               // n*40
    float* emb    = logits + (size_t)n * 40;     // n*128

    const int BT = 256;
    const int nb_nh   = (n * GHEADS + BT - 1) / BT;
    const int nb_edge = (E + BT - 1) / BT;
    const int nb_agg  = (n * 64 + BT - 1) / BT;
    const int nb_scan = (n + 255) / 256;
    const int nb_m    = (n + 31) / 32;

    // ---------------- CSR build (once) ----------------
    hipMemsetAsync(counts, 0, (size_t)n * sizeof(int), stream);
    hist_kernel<<<nb_edge, BT, 0, stream>>>(dst, E, counts);
    bsum_kernel<<<nb_scan, 256, 0, stream>>>(counts, bsum, n);
    bscan_kernel<<<1, 1024, 0, stream>>>(bsum, nb_scan);
    rowptr_kernel<<<nb_scan, 256, 0, stream>>>(counts, bsum, rowptr, n, E);
    hipMemcpyAsync(cursor, rowptr, (size_t)n * sizeof(int), hipMemcpyDeviceToDevice, stream);
    place_kernel<<<nb_edge, BT, 0, stream>>>(src, dst, E, cursor, csrc);

    // ---------------- layer 1 ----------------
    cvtx_kernel<<<(n * 32 + BT - 1) / BT, BT, 0, stream>>>(x, X16, n * 32);
    cvtw_kernel<<<(128 * 128 + BT - 1) / BT, BT, 0, stream>>>(W1, Wt16, 128, 128);
    mgemm_kernel<4><<<nb_m, 256, 0, stream>>>(X16, Wt16, H16, n);
    attdot_kernel<32><<<nb_nh, BT, 0, stream>>>(H16, as1, ad1, asrc, adst, n);
    agg_kernel<128, true, true><<<nb_agg, BT, 0, stream>>>(rowptr, csrc, asrc, adst, H16, b1, X16, nullptr, n);

    // ---------------- layer 2 ----------------
    cvtw_kernel<<<(128 * 128 + BT - 1) / BT, BT, 0, stream>>>(W2, Wt16, 128, 128);
    mgemm_kernel<4><<<nb_m, 256, 0, stream>>>(X16, Wt16, H16, n);
    attdot_kernel<32><<<nb_nh, BT, 0, stream>>>(H16, as2, ad2, asrc, adst, n);
    agg_kernel<128, true, true><<<nb_agg, BT, 0, stream>>>(rowptr, csrc, asrc, adst, H16, b2, X16, emb, n);

    // ---------------- layer 3 ----------------
    cvtw_kernel<<<(160 * 128 + BT - 1) / BT, BT, 0, stream>>>(W3, Wt16, 128, 160);
    mgemm_kernel<5><<<nb_m, 320, 0, stream>>>(X16, Wt16, H16, n);
    attdot_kernel<40><<<nb_nh, BT, 0, stream>>>(H16, as3, ad3, asrc, adst, n);
    agg_kernel<160, false, false><<<nb_agg, BT, 0, stream>>>(rowptr, csrc, asrc, adst, H16, nullptr, B, nullptr, n);
    final_kernel<<<(n + 127) / 128, 128, 0, stream>>>(B, b3, logits, n);
}

// Round 6
// 328.491 us; speedup vs baseline: 4.8828x; 1.1155x over previous
//
#include <hip/hip_runtime.h>
#include <math.h>

#define GHEADS 4
typedef __attribute__((ext_vector_type(8))) short bf16x8;
typedef __attribute__((ext_vector_type(4))) float f32x4;

__device__ __forceinline__ float b2f(ushort u) { return __uint_as_float(((unsigned)u) << 16); }
__device__ __forceinline__ ushort f2b(float f) {
    unsigned u = __float_as_uint(f);
    unsigned r = (u + 0x7fffu + ((u >> 16) & 1u)) >> 16;
    return (ushort)r;
}
__device__ __forceinline__ float lrelu(float a) { return a > 0.f ? a : 0.2f * a; }

// ---------------- W[K][N] fp32 -> Wt16[N][K] bf16 (transpose) ----------------
__global__ void cvtw_kernel(const float* __restrict__ W, ushort* __restrict__ Wt, int K, int N) {
    int i = blockIdx.x * blockDim.x + threadIdx.x;
    if (i >= N * K) return;
    int nn = i / K, k = i - nn * K;
    Wt[i] = f2b(W[k * N + nn]);
}

// ---------------- MFMA GEMM + fused attdot ----------------
// block: 32 rows x N cols; wave w owns cols [w*32, w*32+32).
// Epilogue: fp32 accs staged in LDS (odd stride -> conflict-free), then per-(row,head)
// attention dots computed in-block; H16 written bf16 for the gather.
template<int NW, int C, bool F32IN>
__global__ void __launch_bounds__(NW * 64) mgemm_kernel(const void* __restrict__ Xin,
                                                        const ushort* __restrict__ Wt16,
                                                        ushort* __restrict__ H16,
                                                        const float* __restrict__ as_,
                                                        const float* __restrict__ ad_,
                                                        float* __restrict__ asrc,
                                                        float* __restrict__ adst, int n) {
    constexpr int N = NW * 32;
    constexpr int STR = N + 5;                  // odd (mod 32 == 5): conflict-free rows
    __shared__ float hs[32][STR];
    const int wave = threadIdx.x >> 6;
    const int lane = threadIdx.x & 63;
    const int row0 = blockIdx.x * 32;
    const int col0 = wave * 32;
    const int lr = lane & 15;
    const int lk = (lane >> 4) << 3;

    f32x4 acc00 = {0.f,0.f,0.f,0.f}, acc01 = {0.f,0.f,0.f,0.f};
    f32x4 acc10 = {0.f,0.f,0.f,0.f}, acc11 = {0.f,0.f,0.f,0.f};

    const ushort* Wp = Wt16 + (size_t)(col0 + lr) * 128 + lk;
    if (F32IN) {
        const float* X = (const float*)Xin;
        int r0 = row0 + lr;      if (r0 > n - 1) r0 = n - 1;   // clamp: don't read OOB input
        int r1 = row0 + 16 + lr; if (r1 > n - 1) r1 = n - 1;
        const float* xp0 = X + (size_t)r0 * 128 + lk;
        const float* xp1 = X + (size_t)r1 * 128 + lk;
#pragma unroll
        for (int kk = 0; kk < 4; ++kk) {
            float4 u0 = *(const float4*)(xp0 + kk * 32);
            float4 u1 = *(const float4*)(xp0 + kk * 32 + 4);
            float4 w0 = *(const float4*)(xp1 + kk * 32);
            float4 w1 = *(const float4*)(xp1 + kk * 32 + 4);
            bf16x8 a0, a1;
            a0[0] = (short)f2b(u0.x); a0[1] = (short)f2b(u0.y); a0[2] = (short)f2b(u0.z); a0[3] = (short)f2b(u0.w);
            a0[4] = (short)f2b(u1.x); a0[5] = (short)f2b(u1.y); a0[6] = (short)f2b(u1.z); a0[7] = (short)f2b(u1.w);
            a1[0] = (short)f2b(w0.x); a1[1] = (short)f2b(w0.y); a1[2] = (short)f2b(w0.z); a1[3] = (short)f2b(w0.w);
            a1[4] = (short)f2b(w1.x); a1[5] = (short)f2b(w1.y); a1[6] = (short)f2b(w1.z); a1[7] = (short)f2b(w1.w);
            bf16x8 b0 = *(const bf16x8*)(Wp + kk * 32);
            bf16x8 b1 = *(const bf16x8*)(Wp + 16 * 128 + kk * 32);
            acc00 = __builtin_amdgcn_mfma_f32_16x16x32_bf16(a0, b0, acc00, 0, 0, 0);
            acc10 = __builtin_amdgcn_mfma_f32_16x16x32_bf16(a1, b0, acc10, 0, 0, 0);
            acc01 = __builtin_amdgcn_mfma_f32_16x16x32_bf16(a0, b1, acc01, 0, 0, 0);
            acc11 = __builtin_amdgcn_mfma_f32_16x16x32_bf16(a1, b1, acc11, 0, 0, 0);
        }
    } else {
        const ushort* X16 = (const ushort*)Xin;
        const ushort* xp0 = X16 + (size_t)(row0 + lr) * 128 + lk;   // rows < np: in-buffer
#pragma unroll
        for (int kk = 0; kk < 4; ++kk) {
            bf16x8 a0 = *(const bf16x8*)(xp0 + kk * 32);
            bf16x8 a1 = *(const bf16x8*)(xp0 + 16 * 128 + kk * 32);
            bf16x8 b0 = *(const bf16x8*)(Wp + kk * 32);
            bf16x8 b1 = *(const bf16x8*)(Wp + 16 * 128 + kk * 32);
            acc00 = __builtin_amdgcn_mfma_f32_16x16x32_bf16(a0, b0, acc00, 0, 0, 0);
            acc10 = __builtin_amdgcn_mfma_f32_16x16x32_bf16(a1, b0, acc10, 0, 0, 0);
            acc01 = __builtin_amdgcn_mfma_f32_16x16x32_bf16(a0, b1, acc01, 0, 0, 0);
            acc11 = __builtin_amdgcn_mfma_f32_16x16x32_bf16(a1, b1, acc11, 0, 0, 0);
        }
    }

    // C/D layout: col = lane&15, row = (lane>>4)*4 + reg
    const int rbase = (lane >> 4) * 4;
#pragma unroll
    for (int r = 0; r < 4; ++r) {
        int lrow = rbase + r;
        hs[lrow][col0 + lr]       = acc00[r];
        hs[lrow][col0 + 16 + lr]  = acc01[r];
        hs[lrow + 16][col0 + lr]      = acc10[r];
        hs[lrow + 16][col0 + 16 + lr] = acc11[r];
        int row = row0 + lrow;
        if (row < n) {
            H16[(size_t)row * N + col0 + lr]      = f2b(acc00[r]);
            H16[(size_t)row * N + col0 + 16 + lr] = f2b(acc01[r]);
        }
        int row2 = row + 16;
        if (row2 < n) {
            H16[(size_t)row2 * N + col0 + lr]      = f2b(acc10[r]);
            H16[(size_t)row2 * N + col0 + 16 + lr] = f2b(acc11[r]);
        }
    }
    __syncthreads();
    // fused attdot: threads 0..127 -> (row = t&31, head = t>>5)
    int t = threadIdx.x;
    if (t < 128) {
        int row = t & 31, h = t >> 5;
        int grow = row0 + row;
        if (grow < n) {
            const float* hp = &hs[row][h * C];
            const float* ap = as_ + h * C;
            const float* dp = ad_ + h * C;
            float s1 = 0.f, s2 = 0.f;
#pragma unroll 8
            for (int c = 0; c < C; ++c) { float v = hp[c]; s1 += v * ap[c]; s2 += v * dp[c]; }
            asrc[(unsigned)grow * 4 + h] = s1;
            adst[(unsigned)grow * 4 + h] = s2;
        }
    }
}

// ---------------- CSR build ----------------
__global__ void hist_kernel(const int* __restrict__ dst, int E, int* __restrict__ counts) {
    int i = blockIdx.x * blockDim.x + threadIdx.x;
    if (i < E) atomicAdd(&counts[dst[i]], 1);
}

__global__ void __launch_bounds__(256) bsum_kernel(const int* __restrict__ counts,
                                                   int* __restrict__ bsum, int n) {
    int i = blockIdx.x * 256 + threadIdx.x;
    int v = (i < n) ? counts[i] : 0;
#pragma unroll
    for (int off = 1; off < 64; off <<= 1) v += __shfl_xor(v, off);
    __shared__ int ws_[4];
    if ((threadIdx.x & 63) == 0) ws_[threadIdx.x >> 6] = v;
    __syncthreads();
    if (threadIdx.x == 0) bsum[blockIdx.x] = ws_[0] + ws_[1] + ws_[2] + ws_[3];
}

__global__ void __launch_bounds__(1024) bscan_kernel(int* __restrict__ bsum, int nb) {
    __shared__ int tmp[1024];
    int tid = threadIdx.x;
    int v = (tid < nb) ? bsum[tid] : 0;
    tmp[tid] = v;
    __syncthreads();
    for (int off = 1; off < 1024; off <<= 1) {
        int t = (tid >= off) ? tmp[tid - off] : 0;
        __syncthreads();
        tmp[tid] += t;
        __syncthreads();
    }
    if (tid < nb) bsum[tid] = tmp[tid] - v;
}

// local scan + block offset -> rowptr (exclusive) AND cursor copy; rowptr[n] = E
__global__ void __launch_bounds__(256) rowptr_kernel(const int* __restrict__ counts,
                                                     const int* __restrict__ bsum,
                                                     int* __restrict__ rowptr,
                                                     int* __restrict__ cursor, int n, int E) {
    int i = blockIdx.x * 256 + threadIdx.x;
    int lane = threadIdx.x & 63, wid = threadIdx.x >> 6;
    int v = (i < n) ? counts[i] : 0;
    int x = v;
#pragma unroll
    for (int off = 1; off < 64; off <<= 1) {
        int t = __shfl_up(x, off);
        if (lane >= off) x += t;
    }
    __shared__ int wsum[4];
    if (lane == 63) wsum[wid] = x;
    __syncthreads();
    int woff = 0;
    for (int w = 0; w < 4; ++w) if (w < wid) woff += wsum[w];
    int excl = bsum[blockIdx.x] + woff + (x - v);
    if (i < n) { rowptr[i] = excl; cursor[i] = excl; }
    if (i == n - 1) rowptr[n] = E;
}

__global__ void place_kernel(const int* __restrict__ src, const int* __restrict__ dst,
                             int E, int* __restrict__ cursor, int* __restrict__ csrc) {
    int i = blockIdx.x * blockDim.x + threadIdx.x;
    if (i < E) {
        int p = atomicAdd(&cursor[dst[i]], 1);
        csrc[p] = src[i];
    }
}

// ---------------- fused softmax + gather-aggregate: one wave per dst node ----------------
// single sweep (no max: |alpha| <~ 12 << 88, identical after normalization).
// BF16OUT: write bf16 (next GEMM input). FINAL: head-mean + b3 + log_softmax in-wave.
template<int OUT, bool RELU, bool BF16OUT, bool FINAL>
__global__ void agg_kernel(const int* __restrict__ rowptr, const int* __restrict__ csrc,
                           const float* __restrict__ asrc, const float* __restrict__ adst,
                           const ushort* __restrict__ H16, const float* __restrict__ bias,
                           void* __restrict__ outv, float* __restrict__ emb,
                           const float* __restrict__ b3, int n) {
    constexpr int C = OUT / GHEADS;
    constexpr bool RS2 = (OUT > 128);
    constexpr int UN = 8;
    int wid = (blockIdx.x * blockDim.x + threadIdx.x) >> 6;
    int lane = threadIdx.x & 63;
    if (wid >= n) return;   // n*64 % 256 == 0: never taken, barrier below is safe
    const int d = wid;
    const int h4 = lane & 3;
    const int rs = rowptr[d], re = rowptr[d + 1];
    const int hs0 = (2 * lane) / C;
    const bool act1 = RS2 && (lane < 16);

    const float adv = adst[(unsigned)d * 4 + h4];
    const float aself = lrelu(asrc[(unsigned)d * 4 + h4] + adv);

    float2 acc0 = make_float2(0.f, 0.f);
    float2 acc1 = make_float2(0.f, 0.f);
    float dsum = 0.f;

    {   // self loop
        float w = __expf(aself);
        dsum += w;
        const ushort2* rp = (const ushort2*)H16 + (unsigned)d * (OUT / 2);
        ushort2 v0 = rp[lane];
        float c0 = __shfl(w, hs0);
        acc0.x += c0 * b2f(v0.x); acc0.y += c0 * b2f(v0.y);
        if (RS2) {
            ushort2 v1 = {0, 0};
            if (act1) v1 = rp[64 + lane];
            float c1 = __shfl(w, 3);
            acc1.x += c1 * b2f(v1.x); acc1.y += c1 * b2f(v1.y);
        }
    }

    int i = rs;
    const int nU = (re - rs) / UN * UN;
    for (; i < rs + nU; i += UN) {
        int s[UN];
        float r[UN];
        ushort2 v0[UN], v1[UN];
#pragma unroll
        for (int u = 0; u < UN; ++u) s[u] = csrc[i + u];
#pragma unroll
        for (int u = 0; u < UN; ++u) r[u] = asrc[(unsigned)s[u] * 4 + h4];
#pragma unroll
        for (int u = 0; u < UN; ++u) {
            const ushort2* p = (const ushort2*)H16 + (unsigned)s[u] * (OUT / 2);
            v0[u] = p[lane];
            if (RS2) { v1[u] = act1 ? p[64 + lane] : make_ushort2(0, 0); }
        }
#pragma unroll
        for (int u = 0; u < UN; ++u) {
            float w = __expf(lrelu(r[u] + adv));
            dsum += w;
            float c0 = __shfl(w, hs0);
            acc0.x += c0 * b2f(v0[u].x); acc0.y += c0 * b2f(v0[u].y);
            if (RS2) {
                float c1 = __shfl(w, 3);
                acc1.x += c1 * b2f(v1[u].x); acc1.y += c1 * b2f(v1[u].y);
            }
        }
    }
    for (; i < re; ++i) {
        int s = csrc[i];
        float r = asrc[(unsigned)s * 4 + h4];
        const ushort2* p = (const ushort2*)H16 + (unsigned)s * (OUT / 2);
        ushort2 v0 = p[lane];
        ushort2 v1 = {0, 0};
        if (act1) v1 = p[64 + lane];
        float w = __expf(lrelu(r + adv));
        dsum += w;
        float c0 = __shfl(w, hs0);
        acc0.x += c0 * b2f(v0.x); acc0.y += c0 * b2f(v0.y);
        if (RS2) { float c1 = __shfl(w, 3); acc1.x += c1 * b2f(v1.x); acc1.y += c1 * b2f(v1.y); }
    }

    // ---- epilogue ----
    float inv0 = 1.f / __shfl(dsum, hs0);
    float ox = acc0.x * inv0, oy = acc0.y * inv0;
    if (FINAL) {
        // head-mean + b3 + log_softmax, fully in-block
        __shared__ float fl[4][160];
        int wv = threadIdx.x >> 6;
        fl[wv][2 * lane] = ox; fl[wv][2 * lane + 1] = oy;
        float inv1 = 1.f / __shfl(dsum, 3);
        if (act1) {
            fl[wv][128 + 2 * lane] = acc1.x * inv1;
            fl[wv][129 + 2 * lane] = acc1.y * inv1;
        }
        __syncthreads();
        float* logits = (float*)outv;
        int c = lane;
        float g = -1e30f;
        if (c < 40)
            g = 0.25f * (fl[wv][c] + fl[wv][40 + c] + fl[wv][80 + c] + fl[wv][120 + c]) + b3[c];
        float mx = g;
#pragma unroll
        for (int off = 1; off < 64; off <<= 1) mx = fmaxf(mx, __shfl_xor(mx, off));
        float ev = (c < 40) ? __expf(g - mx) : 0.f;
        float sm = ev;
#pragma unroll
        for (int off = 1; off < 64; off <<= 1) sm += __shfl_xor(sm, off);
        float lg = mx + __logf(sm);
        if (c < 40) logits[(unsigned)d * 40 + c] = g - lg;
    } else {
        int ch0 = 2 * lane;
        if (bias) { ox += bias[ch0]; oy += bias[ch0 + 1]; }
        if (RELU) { ox = fmaxf(ox, 0.f); oy = fmaxf(oy, 0.f); }
        if (BF16OUT) {
            unsigned o = (unsigned)f2b(ox) | ((unsigned)f2b(oy) << 16);
            ((unsigned*)outv)[(unsigned)d * (OUT / 2) + lane] = o;
            if (emb) ((float2*)(emb + (size_t)d * OUT))[lane] = make_float2(ox, oy);
        } else {
            float2* op = (float2*)((float*)outv + (size_t)d * OUT);
            op[lane] = make_float2(ox, oy);
        }
    }
}

extern "C" void kernel_launch(void* const* d_in, const int* in_sizes, int n_in,
                              void* d_out, int out_size, void* d_ws, size_t ws_size,
                              hipStream_t stream) {
    const float* x   = (const float*)d_in[0];
    const int*   ei  = (const int*)d_in[1];
    const float* W1  = (const float*)d_in[2];
    const float* as1 = (const float*)d_in[3];
    const float* ad1 = (const float*)d_in[4];
    const float* b1  = (const float*)d_in[5];
    const float* W2  = (const float*)d_in[6];
    const float* as2 = (const float*)d_in[7];
    const float* ad2 = (const float*)d_in[8];
    const float* b2  = (const float*)d_in[9];
    const float* W3  = (const float*)d_in[10];
    const float* as3 = (const float*)d_in[11];
    const float* ad3 = (const float*)d_in[12];
    const float* b3  = (const float*)d_in[13];

    const int n = in_sizes[0] / 128;      // 50000
    const int E = in_sizes[1] / 2;        // 800000
    const int np = (n + 31) & ~31;        // padded rows for guard-free MFMA loads
    const int* src = ei;
    const int* dst = ei + E;

    // workspace carve (64B aligned)
    char* p = (char*)d_ws;
    auto alloc = [&](size_t bytes) { char* q = p; p += (bytes + 63) & ~(size_t)63; return q; };
    float*  asrc   = (float*)alloc((size_t)n * 4 * 4);
    float*  adst   = (float*)alloc((size_t)n * 4 * 4);
    int*    counts = (int*)alloc((size_t)n * 4);
    int*    rowptr = (int*)alloc((size_t)(n + 1) * 4);
    int*    cursor = (int*)alloc((size_t)n * 4);
    int*    bsum   = (int*)alloc(1024 * 4);
    int*    csrc   = (int*)alloc((size_t)E * 4);
    ushort* X16    = (ushort*)alloc((size_t)np * 128 * 2);
    ushort* H16    = (ushort*)alloc((size_t)np * 160 * 2);
    ushort* Wt16   = (ushort*)alloc((size_t)160 * 128 * 2);

    float* logits = (float*)d_out;               // n*40
    float* emb    = logits + (size_t)n * 40;     // n*128

    const int BT = 256;
    const int nb_edge = (E + BT - 1) / BT;
    const int nb_agg  = (n * 64 + BT - 1) / BT;
    const int nb_scan = (n + 255) / 256;
    const int nb_m    = (n + 31) / 32;

    // ---------------- CSR build (once) ----------------
    hipMemsetAsync(counts, 0, (size_t)n * sizeof(int), stream);
    hist_kernel<<<nb_edge, BT, 0, stream>>>(dst, E, counts);
    bsum_kernel<<<nb_scan, 256, 0, stream>>>(counts, bsum, n);
    bscan_kernel<<<1, 1024, 0, stream>>>(bsum, nb_scan);
    rowptr_kernel<<<nb_scan, 256, 0, stream>>>(counts, bsum, rowptr, cursor, n, E);
    place_kernel<<<nb_edge, BT, 0, stream>>>(src, dst, E, cursor, csrc);

    // ---------------- layer 1 ----------------
    cvtw_kernel<<<(128 * 128 + BT - 1) / BT, BT, 0, stream>>>(W1, Wt16, 128, 128);
    mgemm_kernel<4, 32, true><<<nb_m, 256, 0, stream>>>(x, Wt16, H16, as1, ad1, asrc, adst, n);
    agg_kernel<128, true, true, false><<<nb_agg, BT, 0, stream>>>(rowptr, csrc, asrc, adst, H16, b1, X16, nullptr, nullptr, n);

    // ---------------- layer 2 ----------------
    cvtw_kernel<<<(128 * 128 + BT - 1) / BT, BT, 0, stream>>>(W2, Wt16, 128, 128);
    mgemm_kernel<4, 32, false><<<nb_m, 256, 0, stream>>>(X16, Wt16, H16, as2, ad2, asrc, adst, n);
    agg_kernel<128, true, true, false><<<nb_agg, BT, 0, stream>>>(rowptr, csrc, asrc, adst, H16, b2, X16, emb, nullptr, n);

    // ---------------- layer 3 ----------------
    cvtw_kernel<<<(160 * 128 + BT - 1) / BT, BT, 0, stream>>>(W3, Wt16, 128, 160);
    mgemm_kernel<5, 40, false><<<nb_m, 320, 0, stream>>>(X16, Wt16, H16, as3, ad3, asrc, adst, n);
    agg_kernel<160, false, false, true><<<nb_agg, BT, 0, stream>>>(rowptr, csrc, asrc, adst, H16, nullptr, logits, nullptr, b3, n);
}

// Round 7
// 300.698 us; speedup vs baseline: 5.3341x; 1.0924x over previous
//
#include <hip/hip_runtime.h>
#include <math.h>

#define GHEADS 4
typedef __attribute__((ext_vector_type(8))) short bf16x8;
typedef __attribute__((ext_vector_type(4))) float f32x4;

__device__ __forceinline__ float b2f(ushort u) { return __uint_as_float(((unsigned)u) << 16); }
__device__ __forceinline__ ushort f2b(float f) {
    unsigned u = __float_as_uint(f);
    unsigned r = (u + 0x7fffu + ((u >> 16) & 1u)) >> 16;
    return (ushort)r;
}
__device__ __forceinline__ float lrelu(float a) { return a > 0.f ? a : 0.2f * a; }

// ---------------- all three W[K][N] fp32 -> Wt16[N][K] bf16 (transpose), one launch ----------------
__global__ void cvtw_all(const float* __restrict__ W1, const float* __restrict__ W2,
                         const float* __restrict__ W3, ushort* __restrict__ Wt) {
    int i = blockIdx.x * blockDim.x + threadIdx.x;
    if (i < 16384) {
        int nn = i >> 7, k = i & 127;
        Wt[i] = f2b(W1[k * 128 + nn]);
    } else if (i < 32768) {
        int j = i - 16384; int nn = j >> 7, k = j & 127;
        Wt[i] = f2b(W2[k * 128 + nn]);
    } else if (i < 53248) {
        int j = i - 32768; int nn = j >> 7, k = j & 127;
        Wt[i] = f2b(W3[k * 160 + nn]);
    }
}

// ---------------- MFMA GEMM (64 rows/block) + fused attdot ----------------
template<int NW, int C, bool F32IN>
__global__ void __launch_bounds__(NW * 64) mgemm_kernel(const void* __restrict__ Xin,
                                                        const ushort* __restrict__ Wt16,
                                                        ushort* __restrict__ H16,
                                                        const float* __restrict__ as_,
                                                        const float* __restrict__ ad_,
                                                        float* __restrict__ asrc,
                                                        float* __restrict__ adst, int n) {
    constexpr int N = NW * 32;
    constexpr int STR = N + 5;                 // odd stride: conflict-free columns
    __shared__ float hs[64][STR];
    const int wave = threadIdx.x >> 6;
    const int lane = threadIdx.x & 63;
    const int row0 = blockIdx.x * 64;
    const int col0 = wave * 32;
    const int lr = lane & 15;
    const int lk = (lane >> 4) << 3;

    f32x4 acc[4][2];
#pragma unroll
    for (int g = 0; g < 4; ++g) { acc[g][0] = (f32x4){0.f,0.f,0.f,0.f}; acc[g][1] = (f32x4){0.f,0.f,0.f,0.f}; }

    const ushort* Wp = Wt16 + (size_t)(col0 + lr) * 128 + lk;

    if (F32IN) {
        const float* X = (const float*)Xin;
        const float* xp[4];
#pragma unroll
        for (int g = 0; g < 4; ++g) {
            int r = row0 + g * 16 + lr; if (r > n - 1) r = n - 1;
            xp[g] = X + (size_t)r * 128 + lk;
        }
#pragma unroll
        for (int kk = 0; kk < 4; ++kk) {
            bf16x8 b0 = *(const bf16x8*)(Wp + kk * 32);
            bf16x8 b1 = *(const bf16x8*)(Wp + 16 * 128 + kk * 32);
#pragma unroll
            for (int g = 0; g < 4; ++g) {
                float4 u0 = *(const float4*)(xp[g] + kk * 32);
                float4 u1 = *(const float4*)(xp[g] + kk * 32 + 4);
                bf16x8 a;
                a[0] = (short)f2b(u0.x); a[1] = (short)f2b(u0.y); a[2] = (short)f2b(u0.z); a[3] = (short)f2b(u0.w);
                a[4] = (short)f2b(u1.x); a[5] = (short)f2b(u1.y); a[6] = (short)f2b(u1.z); a[7] = (short)f2b(u1.w);
                acc[g][0] = __builtin_amdgcn_mfma_f32_16x16x32_bf16(a, b0, acc[g][0], 0, 0, 0);
                acc[g][1] = __builtin_amdgcn_mfma_f32_16x16x32_bf16(a, b1, acc[g][1], 0, 0, 0);
            }
        }
    } else {
        const ushort* X16 = (const ushort*)Xin;
        const ushort* xp[4];
#pragma unroll
        for (int g = 0; g < 4; ++g) xp[g] = X16 + (size_t)(row0 + g * 16 + lr) * 128 + lk;
#pragma unroll
        for (int kk = 0; kk < 4; ++kk) {
            bf16x8 b0 = *(const bf16x8*)(Wp + kk * 32);
            bf16x8 b1 = *(const bf16x8*)(Wp + 16 * 128 + kk * 32);
#pragma unroll
            for (int g = 0; g < 4; ++g) {
                bf16x8 a = *(const bf16x8*)(xp[g] + kk * 32);
                acc[g][0] = __builtin_amdgcn_mfma_f32_16x16x32_bf16(a, b0, acc[g][0], 0, 0, 0);
                acc[g][1] = __builtin_amdgcn_mfma_f32_16x16x32_bf16(a, b1, acc[g][1], 0, 0, 0);
            }
        }
    }

    // C/D: col = lane&15, row = (lane>>4)*4 + reg
    const int rb = (lane >> 4) * 4;
#pragma unroll
    for (int g = 0; g < 4; ++g) {
#pragma unroll
        for (int r = 0; r < 4; ++r) {
            int lrow = g * 16 + rb + r;
            hs[lrow][col0 + lr]      = acc[g][0][r];
            hs[lrow][col0 + 16 + lr] = acc[g][1][r];
            int grow = row0 + lrow;
            if (grow < n) {
                H16[(size_t)grow * N + col0 + lr]      = f2b(acc[g][0][r]);
                H16[(size_t)grow * N + col0 + 16 + lr] = f2b(acc[g][1][r]);
            }
        }
    }
    __syncthreads();
    // fused attdot: threads 0..255 -> (row = t&63, head = t>>6)
    int t = threadIdx.x;
    if (t < 256) {
        int row = t & 63, h = t >> 6;
        int grow = row0 + row;
        if (grow < n) {
            const float* hp = &hs[row][h * C];
            const float* ap = as_ + h * C;
            const float* dp = ad_ + h * C;
            float s1 = 0.f, s2 = 0.f;
#pragma unroll 8
            for (int c = 0; c < C; ++c) { float v = hp[c]; s1 += v * ap[c]; s2 += v * dp[c]; }
            asrc[(unsigned)grow * 4 + h] = s1;
            adst[(unsigned)grow * 4 + h] = s2;
        }
    }
}

// ---------------- CSR build ----------------
__global__ void hist_kernel(const int* __restrict__ dst, int E, int* __restrict__ counts) {
    int i = blockIdx.x * blockDim.x + threadIdx.x;
    if (i < E) atomicAdd(&counts[dst[i]], 1);
}

__global__ void __launch_bounds__(256) bsum_kernel(const int* __restrict__ counts,
                                                   int* __restrict__ bsum, int n) {
    int i = blockIdx.x * 256 + threadIdx.x;
    int v = (i < n) ? counts[i] : 0;
#pragma unroll
    for (int off = 1; off < 64; off <<= 1) v += __shfl_xor(v, off);
    __shared__ int ws_[4];
    if ((threadIdx.x & 63) == 0) ws_[threadIdx.x >> 6] = v;
    __syncthreads();
    if (threadIdx.x == 0) bsum[blockIdx.x] = ws_[0] + ws_[1] + ws_[2] + ws_[3];
}

__global__ void __launch_bounds__(1024) bscan_kernel(int* __restrict__ bsum, int nb) {
    __shared__ int tmp[1024];
    int tid = threadIdx.x;
    int v = (tid < nb) ? bsum[tid] : 0;
    tmp[tid] = v;
    __syncthreads();
    for (int off = 1; off < 1024; off <<= 1) {
        int t = (tid >= off) ? tmp[tid - off] : 0;
        __syncthreads();
        tmp[tid] += t;
        __syncthreads();
    }
    if (tid < nb) bsum[tid] = tmp[tid] - v;
}

__global__ void __launch_bounds__(256) rowptr_kernel(const int* __restrict__ counts,
                                                     const int* __restrict__ bsum,
                                                     int* __restrict__ rowptr,
                                                     int* __restrict__ cursor, int n, int E) {
    int i = blockIdx.x * 256 + threadIdx.x;
    int lane = threadIdx.x & 63, wid = threadIdx.x >> 6;
    int v = (i < n) ? counts[i] : 0;
    int x = v;
#pragma unroll
    for (int off = 1; off < 64; off <<= 1) {
        int t = __shfl_up(x, off);
        if (lane >= off) x += t;
    }
    __shared__ int wsum[4];
    if (lane == 63) wsum[wid] = x;
    __syncthreads();
    int woff = 0;
    for (int w = 0; w < 4; ++w) if (w < wid) woff += wsum[w];
    int excl = bsum[blockIdx.x] + woff + (x - v);
    if (i < n) { rowptr[i] = excl; cursor[i] = excl; }
    if (i == n - 1) rowptr[n] = E;
}

__global__ void place_kernel(const int* __restrict__ src, const int* __restrict__ dst,
                             int E, int* __restrict__ cursor, int* __restrict__ csrc) {
    int i = blockIdx.x * blockDim.x + threadIdx.x;
    if (i < E) {
        int p = atomicAdd(&cursor[dst[i]], 1);
        csrc[p] = src[i];
    }
}

// ---------------- dual-edge fused softmax + gather-aggregate: one wave per dst node ----------------
// lanes 0-31 process edge i, lanes 32-63 edge i+1; each lane owns 4 channels (ushort4).
// single sweep, no max-sub (|alpha| << 88; identical after normalization).
template<int OUT, bool RELU, bool BF16OUT, bool FINAL>
__global__ void __launch_bounds__(256) agg_kernel(const int* __restrict__ rowptr,
                                                  const int* __restrict__ csrc,
                                                  const float* __restrict__ asrc,
                                                  const float* __restrict__ adst,
                                                  const ushort* __restrict__ H16,
                                                  const float* __restrict__ bias,
                                                  void* __restrict__ outv,
                                                  float* __restrict__ emb,
                                                  const float* __restrict__ b3, int n) {
    constexpr int C = OUT / GHEADS;
    int wid = (blockIdx.x * blockDim.x + threadIdx.x) >> 6;
    int lane = threadIdx.x & 63;
    if (wid >= n) return;
    const int d = wid;
    const int hl = lane >> 5;        // half id (0: even edges, 1: odd edges)
    const int l = lane & 31;
    const int h4 = l & 3;            // head this lane computes exp for
    const int hm = (4 * l) / C;      // head of this lane's 4 main channels
    const int rs = rowptr[d], re = rowptr[d + 1];
    const float adv = adst[(unsigned)d * 4 + h4];

    float acc0 = 0.f, acc1 = 0.f, acc2 = 0.f, acc3 = 0.f;
    float accx = 0.f, accy = 0.f;
    float dsum = 0.f;

    // prologue: half0 = self-loop, half1 = first real edge (if any)
    {
        int s = d;
        if (hl) s = (re > rs) ? csrc[rs] : d;
        float r = asrc[(unsigned)s * 4 + h4];
        float w = __expf(lrelu(r + adv));
        if (hl && re <= rs) w = 0.f;
        dsum += w;
        float cm = __shfl(w, (hl << 5) + hm);
        const ushort* base = H16 + (unsigned)s * OUT;
        ushort4 v = *(const ushort4*)(base + 4 * l);
        acc0 += cm * b2f(v.x); acc1 += cm * b2f(v.y); acc2 += cm * b2f(v.z); acc3 += cm * b2f(v.w);
        if (OUT > 128) {
            float cx = __shfl(w, (hl << 5) + 3);
            ushort2 vx = (l < 16) ? *(const ushort2*)(base + 128 + 2 * l) : make_ushort2(0, 0);
            accx += cx * b2f(vx.x); accy += cx * b2f(vx.y);
        }
    }

    int i = rs + 1;
    for (; i + 7 < re; i += 8) {      // 4 pairs = 8 edges
        int s[4]; float r[4]; ushort4 v[4]; ushort2 vx[4];
#pragma unroll
        for (int u = 0; u < 4; ++u) s[u] = csrc[i + 2 * u + hl];
#pragma unroll
        for (int u = 0; u < 4; ++u) r[u] = asrc[(unsigned)s[u] * 4 + h4];
#pragma unroll
        for (int u = 0; u < 4; ++u) {
            const ushort* base = H16 + (unsigned)s[u] * OUT;
            v[u] = *(const ushort4*)(base + 4 * l);
            if (OUT > 128) vx[u] = (l < 16) ? *(const ushort2*)(base + 128 + 2 * l) : make_ushort2(0, 0);
        }
#pragma unroll
        for (int u = 0; u < 4; ++u) {
            float w = __expf(lrelu(r[u] + adv));
            dsum += w;
            float cm = __shfl(w, (hl << 5) + hm);
            acc0 += cm * b2f(v[u].x); acc1 += cm * b2f(v[u].y);
            acc2 += cm * b2f(v[u].z); acc3 += cm * b2f(v[u].w);
            if (OUT > 128) {
                float cx = __shfl(w, (hl << 5) + 3);
                accx += cx * b2f(vx[u].x); accy += cx * b2f(vx[u].y);
            }
        }
    }
    for (; i + 1 < re; i += 2) {      // single pair
        int s = csrc[i + hl];
        float r = asrc[(unsigned)s * 4 + h4];
        const ushort* base = H16 + (unsigned)s * OUT;
        ushort4 v = *(const ushort4*)(base + 4 * l);
        ushort2 vx = make_ushort2(0, 0);
        if (OUT > 128) vx = (l < 16) ? *(const ushort2*)(base + 128 + 2 * l) : make_ushort2(0, 0);
        float w = __expf(lrelu(r + adv));
        dsum += w;
        float cm = __shfl(w, (hl << 5) + hm);
        acc0 += cm * b2f(v.x); acc1 += cm * b2f(v.y); acc2 += cm * b2f(v.z); acc3 += cm * b2f(v.w);
        if (OUT > 128) {
            float cx = __shfl(w, (hl << 5) + 3);
            accx += cx * b2f(vx.x); accy += cx * b2f(vx.y);
        }
    }
    if (i < re) {                     // odd tail: half0 only
        int s = csrc[i];
        float r = asrc[(unsigned)s * 4 + h4];
        const ushort* base = H16 + (unsigned)s * OUT;
        ushort4 v = *(const ushort4*)(base + 4 * l);
        ushort2 vx = make_ushort2(0, 0);
        if (OUT > 128) vx = (l < 16) ? *(const ushort2*)(base + 128 + 2 * l) : make_ushort2(0, 0);
        float w = (hl == 0) ? __expf(lrelu(r + adv)) : 0.f;
        dsum += w;
        float cm = __shfl(w, (hl << 5) + hm);
        acc0 += cm * b2f(v.x); acc1 += cm * b2f(v.y); acc2 += cm * b2f(v.z); acc3 += cm * b2f(v.w);
        if (OUT > 128) {
            float cx = __shfl(w, (hl << 5) + 3);
            accx += cx * b2f(vx.x); accy += cx * b2f(vx.y);
        }
    }

    // ---- combine halves ----
    acc0 += __shfl_xor(acc0, 32); acc1 += __shfl_xor(acc1, 32);
    acc2 += __shfl_xor(acc2, 32); acc3 += __shfl_xor(acc3, 32);
    dsum += __shfl_xor(dsum, 32);
    if (OUT > 128) { accx += __shfl_xor(accx, 32); accy += __shfl_xor(accy, 32); }

    float invm = 1.f / __shfl(dsum, hm);
    float o0 = acc0 * invm, o1 = acc1 * invm, o2 = acc2 * invm, o3 = acc3 * invm;

    if (FINAL) {
        // head-mean + b3 + log_softmax, barrier-free via shuffles
        float inv3 = 1.f / __shfl(dsum, 3);
        float oE0 = accx * inv3, oE1 = accy * inv3;   // ch 128+2l, 129+2l (valid l<16)
        int c = lane;
        int j = c & 3;
        int s0 = c >> 2;
        float a0, a1, a2, a3m;
        {
            float t0 = __shfl(o0, s0), t1 = __shfl(o1, s0), t2 = __shfl(o2, s0), t3 = __shfl(o3, s0);
            a0 = (j == 0) ? t0 : (j == 1) ? t1 : (j == 2) ? t2 : t3;
        }
        {
            float t0 = __shfl(o0, s0 + 10), t1 = __shfl(o1, s0 + 10), t2 = __shfl(o2, s0 + 10), t3 = __shfl(o3, s0 + 10);
            a1 = (j == 0) ? t0 : (j == 1) ? t1 : (j == 2) ? t2 : t3;
        }
        {
            float t0 = __shfl(o0, s0 + 20), t1 = __shfl(o1, s0 + 20), t2 = __shfl(o2, s0 + 20), t3 = __shfl(o3, s0 + 20);
            a2 = (j == 0) ? t0 : (j == 1) ? t1 : (j == 2) ? t2 : t3;
        }
        {
            float t0 = __shfl(o0, s0 + 30), t1 = __shfl(o1, s0 + 30), t2 = __shfl(o2, s0 + 30), t3 = __shfl(o3, s0 + 30);
            a3m = (j == 0) ? t0 : (j == 1) ? t1 : (j == 2) ? t2 : t3;
        }
        int srcE = (c >= 8) ? ((c - 8) >> 1) : 0;
        float bx = __shfl(oE0, srcE), by = __shfl(oE1, srcE);
        float aE = (c & 1) ? by : bx;
        float a3 = (c < 8) ? a3m : aE;
        float g = (c < 40) ? 0.25f * (a0 + a1 + a2 + a3) + b3[c] : -1e30f;
        float mx = g;
#pragma unroll
        for (int off = 1; off < 64; off <<= 1) mx = fmaxf(mx, __shfl_xor(mx, off));
        float ev = (c < 40) ? __expf(g - mx) : 0.f;
        float sm = ev;
#pragma unroll
        for (int off = 1; off < 64; off <<= 1) sm += __shfl_xor(sm, off);
        float lg = mx + __logf(sm);
        if (c < 40) ((float*)outv)[(unsigned)d * 40 + c] = g - lg;
    } else {
        float4 bv = ((const float4*)bias)[l];
        o0 += bv.x; o1 += bv.y; o2 += bv.z; o3 += bv.w;
        if (RELU) { o0 = fmaxf(o0, 0.f); o1 = fmaxf(o1, 0.f); o2 = fmaxf(o2, 0.f); o3 = fmaxf(o3, 0.f); }
        if (hl == 0) {
            if (BF16OUT) {
                uint2 pk;
                pk.x = (uint)f2b(o0) | ((uint)f2b(o1) << 16);
                pk.y = (uint)f2b(o2) | ((uint)f2b(o3) << 16);
                ((uint2*)outv)[(unsigned)d * (OUT / 4) + l] = pk;
            } else {
                ((float4*)outv)[(unsigned)d * (OUT / 4) + l] = make_float4(o0, o1, o2, o3);
            }
            if (emb) ((float4*)emb)[(unsigned)d * (OUT / 4) + l] = make_float4(o0, o1, o2, o3);
        }
    }
}

extern "C" void kernel_launch(void* const* d_in, const int* in_sizes, int n_in,
                              void* d_out, int out_size, void* d_ws, size_t ws_size,
                              hipStream_t stream) {
    const float* x   = (const float*)d_in[0];
    const int*   ei  = (const int*)d_in[1];
    const float* W1  = (const float*)d_in[2];
    const float* as1 = (const float*)d_in[3];
    const float* ad1 = (const float*)d_in[4];
    const float* b1  = (const float*)d_in[5];
    const float* W2  = (const float*)d_in[6];
    const float* as2 = (const float*)d_in[7];
    const float* ad2 = (const float*)d_in[8];
    const float* b2  = (const float*)d_in[9];
    const float* W3  = (const float*)d_in[10];
    const float* as3 = (const float*)d_in[11];
    const float* ad3 = (const float*)d_in[12];
    const float* b3  = (const float*)d_in[13];

    const int n = in_sizes[0] / 128;      // 50000
    const int E = in_sizes[1] / 2;        // 800000
    const int np = (n + 63) & ~63;        // padded rows (64-row GEMM blocks)
    const int* src = ei;
    const int* dst = ei + E;

    char* p = (char*)d_ws;
    auto alloc = [&](size_t bytes) { char* q = p; p += (bytes + 63) & ~(size_t)63; return q; };
    float*  asrc   = (float*)alloc((size_t)n * 4 * 4);
    float*  adst   = (float*)alloc((size_t)n * 4 * 4);
    int*    counts = (int*)alloc((size_t)n * 4);
    int*    rowptr = (int*)alloc((size_t)(n + 1) * 4);
    int*    cursor = (int*)alloc((size_t)n * 4);
    int*    bsum   = (int*)alloc(1024 * 4);
    int*    csrc   = (int*)alloc((size_t)E * 4);
    ushort* X16    = (ushort*)alloc((size_t)np * 128 * 2);
    ushort* H16    = (ushort*)alloc((size_t)np * 160 * 2);
    ushort* Wt16   = (ushort*)alloc((size_t)(16384 + 16384 + 20480) * 2);

    float* logits = (float*)d_out;               // n*40
    float* emb    = logits + (size_t)n * 40;     // n*128

    const int BT = 256;
    const int nb_edge = (E + BT - 1) / BT;
    const int nb_agg  = (n * 64 + BT - 1) / BT;
    const int nb_scan = (n + 255) / 256;
    const int nb_m    = (n + 63) / 64;

    // ---------------- CSR build (once) ----------------
    hipMemsetAsync(counts, 0, (size_t)n * sizeof(int), stream);
    hist_kernel<<<nb_edge, BT, 0, stream>>>(dst, E, counts);
    bsum_kernel<<<nb_scan, 256, 0, stream>>>(counts, bsum, n);
    bscan_kernel<<<1, 1024, 0, stream>>>(bsum, nb_scan);
    rowptr_kernel<<<nb_scan, 256, 0, stream>>>(counts, bsum, rowptr, cursor, n, E);
    place_kernel<<<nb_edge, BT, 0, stream>>>(src, dst, E, cursor, csrc);
    cvtw_all<<<(53248 + BT - 1) / BT, BT, 0, stream>>>(W1, W2, W3, Wt16);

    // ---------------- layer 1 ----------------
    mgemm_kernel<4, 32, true><<<nb_m, 256, 0, stream>>>(x, Wt16, H16, as1, ad1, asrc, adst, n);
    agg_kernel<128, true, true, false><<<nb_agg, BT, 0, stream>>>(rowptr, csrc, asrc, adst, H16, b1, X16, nullptr, nullptr, n);

    // ---------------- layer 2 ----------------
    mgemm_kernel<4, 32, false><<<nb_m, 256, 0, stream>>>(X16, Wt16 + 16384, H16, as2, ad2, asrc, adst, n);
    agg_kernel<128, true, true, false><<<nb_agg, BT, 0, stream>>>(rowptr, csrc, asrc, adst, H16, b2, X16, emb, nullptr, n);

    // ---------------- layer 3 ----------------
    mgemm_kernel<5, 40, false><<<nb_m, 320, 0, stream>>>(X16, Wt16 + 32768, H16, as3, ad3, asrc, adst, n);
    agg_kernel<160, false, false, true><<<nb_agg, BT, 0, stream>>>(rowptr, csrc, asrc, adst, H16, nullptr, logits, nullptr, b3, n);
}